// Round 1
// baseline (3861.337 us; speedup 1.0000x reference)
//
#include <hip/hip_runtime.h>
#include <math.h>

#define N_NODES 50000
#define E_EDGES 800000
#define KD 128

__device__ __forceinline__ float sigmoidf_(float x) { return 1.f / (1.f + expf(-x)); }

// ---------------------------------------------------------------------------
// Transpose the two GatedGraphConv weight matrices [2][128][128] (k-major ->
// j-major) so the generic GEMM can dot rows.
// ---------------------------------------------------------------------------
__global__ __launch_bounds__(256) void transpose_wg(const float* __restrict__ W,
                                                    float* __restrict__ WT) {
    int t = blockIdx.x * 256 + threadIdx.x;   // 2*128*128 = 32768 total
    int l = t >> 14;
    int r = (t >> 7) & 127;
    int c = t & 127;
    WT[l * 16384 + c * 128 + r] = W[l * 16384 + r * 128 + c];
}

// ---------------------------------------------------------------------------
// Generic fp32 GEMM: out[n, ocol0 + j] (+)= dot(A[n,:], W[j,:]) + bias[j]
//   A: [M][128] row-major, W: [J][128] row-major (dot rows), J = 64*gridDim.y
//   64x64 tile per block, 4x4 per thread, LDS tiles stored k-major (transposed)
//   so the inner loop reads are conflict-light float4s.
// ---------------------------------------------------------------------------
template <bool ACCUM, bool RELUA>
__global__ __launch_bounds__(256) void gemm_tn(const float* __restrict__ A,
                                               const float* __restrict__ W,
                                               const float* __restrict__ bias,
                                               float* __restrict__ out,
                                               int M, int ldo, int ocol0) {
    __shared__ float As[KD][68];   // [k][row]  (68 = 64 + 4 pad)
    __shared__ float Ws[KD][68];   // [k][j]
    const int tid = threadIdx.x;
    const int row0 = blockIdx.x * 64;
    const int jc0 = blockIdx.y * 64;

#pragma unroll
    for (int i = 0; i < 8; ++i) {
        int f4 = tid + i * 256;          // 0..2047 float4 slots
        int r = f4 >> 5;                 // local row 0..63
        int c4 = (f4 & 31) << 2;         // k 0..124
        int gr = row0 + r;
        float4 v = make_float4(0.f, 0.f, 0.f, 0.f);
        if (gr < M) v = *(const float4*)(A + (size_t)gr * KD + c4);
        if (RELUA) {
            v.x = fmaxf(v.x, 0.f); v.y = fmaxf(v.y, 0.f);
            v.z = fmaxf(v.z, 0.f); v.w = fmaxf(v.w, 0.f);
        }
        As[c4 + 0][r] = v.x; As[c4 + 1][r] = v.y;
        As[c4 + 2][r] = v.z; As[c4 + 3][r] = v.w;
    }
#pragma unroll
    for (int i = 0; i < 8; ++i) {
        int f4 = tid + i * 256;
        int r = f4 >> 5;                 // local j 0..63
        int c4 = (f4 & 31) << 2;         // k
        float4 v = *(const float4*)(W + (size_t)(jc0 + r) * KD + c4);
        Ws[c4 + 0][r] = v.x; Ws[c4 + 1][r] = v.y;
        Ws[c4 + 2][r] = v.z; Ws[c4 + 3][r] = v.w;
    }
    __syncthreads();

    const int tx4 = (tid & 15) << 2;   // col group
    const int ty4 = (tid >> 4) << 2;   // row group
    float acc[4][4] = {};
#pragma unroll 8
    for (int k = 0; k < KD; ++k) {
        float4 av = *(const float4*)&As[k][ty4];
        float4 wv = *(const float4*)&Ws[k][tx4];
        acc[0][0] += av.x * wv.x; acc[0][1] += av.x * wv.y;
        acc[0][2] += av.x * wv.z; acc[0][3] += av.x * wv.w;
        acc[1][0] += av.y * wv.x; acc[1][1] += av.y * wv.y;
        acc[1][2] += av.y * wv.z; acc[1][3] += av.y * wv.w;
        acc[2][0] += av.z * wv.x; acc[2][1] += av.z * wv.y;
        acc[2][2] += av.z * wv.z; acc[2][3] += av.z * wv.w;
        acc[3][0] += av.w * wv.x; acc[3][1] += av.w * wv.y;
        acc[3][2] += av.w * wv.z; acc[3][3] += av.w * wv.w;
    }

#pragma unroll
    for (int i = 0; i < 4; ++i) {
        int gr = row0 + ty4 + i;
        if (gr >= M) continue;
        float* op = out + (size_t)gr * ldo + ocol0 + jc0 + tx4;
#pragma unroll
        for (int j = 0; j < 4; ++j) {
            float v = acc[i][j];
            if (bias) v += bias[jc0 + tx4 + j];
            if (ACCUM) op[j] += v; else op[j] = v;
        }
    }
}

// ---------------------------------------------------------------------------
// Edge scatter: agg[dst,:] += ew[e] * m[src,:]   (32 threads per edge, float4)
// ---------------------------------------------------------------------------
__global__ __launch_bounds__(256) void scatter_kernel(const float* __restrict__ m,
                                                      const int* __restrict__ ei,
                                                      const float* __restrict__ ew,
                                                      float* __restrict__ agg) {
    int tid = blockIdx.x * 256 + threadIdx.x;
    int e = tid >> 5;
    if (e >= E_EDGES) return;
    int f0 = (tid & 31) << 2;
    int src = ei[e];
    int dst = ei[E_EDGES + e];
    float w = ew[e];
    float4 v = *(const float4*)(m + (size_t)src * KD + f0);
    float* p = agg + (size_t)dst * KD + f0;
    atomicAdd(p + 0, v.x * w);
    atomicAdd(p + 1, v.y * w);
    atomicAdd(p + 2, v.z * w);
    atomicAdd(p + 3, v.w * w);
}

// ---------------------------------------------------------------------------
// GRU elementwise. G layout per node (512): [0:128]=i_r+h_r, [128:256]=i_z+h_z,
// [256:384]=i_n, [384:512]=h_n
// ---------------------------------------------------------------------------
__global__ __launch_bounds__(256) void gru_elem(const float* __restrict__ G,
                                                const float* __restrict__ hin,
                                                float* __restrict__ hout) {
    int t = blockIdx.x * 256 + threadIdx.x;
    if (t >= N_NODES * KD) return;
    int n = t >> 7;
    int j = t & 127;
    const float* g = G + (size_t)n * 512;
    float r = sigmoidf_(g[j]);
    float z = sigmoidf_(g[128 + j]);
    float nc = tanhf(g[256 + j] + r * g[384 + j]);
    hout[t] = (1.f - z) * nc + z * hin[t];
}

// ---------------------------------------------------------------------------
// LSTM elementwise. G layout per node (512): i, f, g, o
// ---------------------------------------------------------------------------
__global__ __launch_bounds__(256) void lstm_elem(const float* __restrict__ G,
                                                 const float* __restrict__ C,
                                                 float* __restrict__ hout,
                                                 float* __restrict__ cout) {
    int t = blockIdx.x * 256 + threadIdx.x;
    if (t >= N_NODES * KD) return;
    int n = t >> 7;
    int j = t & 127;
    const float* g = G + (size_t)n * 512;
    float ig = sigmoidf_(g[j]);
    float fg = sigmoidf_(g[128 + j]);
    float gg = tanhf(g[256 + j]);
    float og = sigmoidf_(g[384 + j]);
    float c = fg * C[t] + ig * gg;
    hout[t] = og * tanhf(c);
    cout[t] = c;
}

extern "C" void kernel_launch(void* const* d_in, const int* in_sizes, int n_in,
                              void* d_out, int out_size, void* d_ws, size_t ws_size,
                              hipStream_t stream) {
    const float* x        = (const float*)d_in[0];
    const int*   ei       = (const int*)d_in[1];
    const float* ew       = (const float*)d_in[2];
    const float* H        = (const float*)d_in[3];
    const float* C        = (const float*)d_in[4];
    const float* ggc_w    = (const float*)d_in[5];
    const float* gru_wih  = (const float*)d_in[6];
    const float* gru_whh  = (const float*)d_in[7];
    const float* gru_bih  = (const float*)d_in[8];
    const float* gru_bhh  = (const float*)d_in[9];
    const float* lstm_wih = (const float*)d_in[10];
    const float* lstm_whh = (const float*)d_in[11];
    const float* lstm_bih = (const float*)d_in[12];
    const float* lstm_bhh = (const float*)d_in[13];
    const float* lin_w    = (const float*)d_in[14];
    const float* lin_b    = (const float*)d_in[15];

    // d_out regions double as scratch; fully rewritten with final values.
    float* out_head = (float*)d_out;                        // [N][64]
    float* hbuf = out_head + (size_t)N_NODES * 64;          // h_new region [N][128]
    float* mbuf = hbuf + (size_t)N_NODES * KD;              // c_new region [N][128]

    // workspace: agg [N][128], G [N][512], wgT [2][128][128]  (~128.1 MB)
    float* agg = (float*)d_ws;
    float* G   = agg + (size_t)N_NODES * KD;
    float* wgT = G + (size_t)N_NODES * 512;

    dim3 blk(256);
    const int MT = (N_NODES + 63) / 64;   // 782 row tiles

    transpose_wg<<<128, blk, 0, stream>>>(ggc_w, wgT);

    const float* hcur = x;
    for (int layer = 0; layer < 2; ++layer) {
        // m = h @ Wg[layer]
        gemm_tn<false, false><<<dim3(MT, 2), blk, 0, stream>>>(
            hcur, wgT + (size_t)layer * KD * KD, nullptr, mbuf, N_NODES, KD, 0);
        // agg = segment_sum(m[src] * w, dst)
        hipMemsetAsync(agg, 0, (size_t)N_NODES * KD * sizeof(float), stream);
        scatter_kernel<<<(E_EDGES * 32) / 256, blk, 0, stream>>>(mbuf, ei, ew, agg);
        // G[:,0:384]  = agg @ wih^T + bih
        gemm_tn<false, false><<<dim3(MT, 6), blk, 0, stream>>>(
            agg, gru_wih, gru_bih, G, N_NODES, 512, 0);
        // G[:,0:256] += h @ whh[0:256]^T + bhh[0:256]
        gemm_tn<true, false><<<dim3(MT, 4), blk, 0, stream>>>(
            hcur, gru_whh, gru_bhh, G, N_NODES, 512, 0);
        // G[:,384:512] = h @ whh[256:384]^T + bhh[256:384]
        gemm_tn<false, false><<<dim3(MT, 2), blk, 0, stream>>>(
            hcur, gru_whh + 256 * KD, gru_bhh + 256, G, N_NODES, 512, 384);
        gru_elem<<<(N_NODES * KD + 255) / 256, blk, 0, stream>>>(G, hcur, hbuf);
        hcur = hbuf;
    }

    // LSTM gates: G = h @ lstm_wih^T + bih + hx @ lstm_whh^T + bhh
    gemm_tn<false, false><<<dim3(MT, 8), blk, 0, stream>>>(
        hbuf, lstm_wih, lstm_bih, G, N_NODES, 512, 0);
    gemm_tn<true, false><<<dim3(MT, 8), blk, 0, stream>>>(
        H, lstm_whh, lstm_bhh, G, N_NODES, 512, 0);
    lstm_elem<<<(N_NODES * KD + 255) / 256, blk, 0, stream>>>(G, C, hbuf, mbuf);

    // head: out = relu(h_new) @ lin_w^T + lin_b
    gemm_tn<false, true><<<dim3(MT, 1), blk, 0, stream>>>(
        hbuf, lin_w, lin_b, out_head, N_NODES, 64, 0);
}

// Round 2
// 1457.342 us; speedup vs baseline: 2.6496x; 2.6496x over previous
//
#include <hip/hip_runtime.h>
#include <math.h>

#define N_NODES 50000
#define E_EDGES 800000
#define KD 128

__device__ __forceinline__ float sigmoidf_(float x) { return 1.f / (1.f + expf(-x)); }

// ---------------------------------------------------------------------------
// Transpose the two GatedGraphConv weight matrices [2][128][128]
// ---------------------------------------------------------------------------
__global__ __launch_bounds__(256) void transpose_wg(const float* __restrict__ W,
                                                    float* __restrict__ WT) {
    int t = blockIdx.x * 256 + threadIdx.x;
    int l = t >> 14;
    int r = (t >> 7) & 127;
    int c = t & 127;
    WT[l * 16384 + c * 128 + r] = W[l * 16384 + r * 128 + c];
}

// ---------------------------------------------------------------------------
// CSR build: degree histogram -> single-WG scan -> fill sorted src/weight
// ---------------------------------------------------------------------------
__global__ __launch_bounds__(256) void count_deg(const int* __restrict__ ei,
                                                 int* __restrict__ deg) {
    int e = blockIdx.x * 256 + threadIdx.x;
    if (e >= E_EDGES) return;
    atomicAdd(&deg[ei[E_EDGES + e]], 1);
}

// deg lives in `cursor`; this kernel reads deg, writes rowptr (exclusive scan)
// and rewrites cursor = rowptr[i] (fill cursors). One workgroup of 1024.
#define SCAN_CHUNK 49
__global__ __launch_bounds__(1024) void scan_deg(int* __restrict__ cursor,
                                                 int* __restrict__ rowptr) {
    __shared__ int part[1024];
    const int t = threadIdx.x;
    const int base = t * SCAN_CHUNK;
    int sum = 0;
    for (int i = 0; i < SCAN_CHUNK; ++i) {
        int idx = base + i;
        if (idx < N_NODES) sum += cursor[idx];
    }
    part[t] = sum;
    __syncthreads();
    // Hillis-Steele inclusive scan over 1024 partials
    for (int off = 1; off < 1024; off <<= 1) {
        int v = (t >= off) ? part[t - off] : 0;
        __syncthreads();
        part[t] += v;
        __syncthreads();
    }
    int running = part[t] - sum;   // exclusive base for this chunk
    for (int i = 0; i < SCAN_CHUNK; ++i) {
        int idx = base + i;
        if (idx < N_NODES) {
            int d = cursor[idx];
            rowptr[idx] = running;
            cursor[idx] = running;
            running += d;
        }
    }
    if (t == 1023) rowptr[N_NODES] = part[1023];
}

__global__ __launch_bounds__(256) void fill_csr(const int* __restrict__ ei,
                                                const float* __restrict__ ew,
                                                int* __restrict__ cursor,
                                                int* __restrict__ sSrc,
                                                float* __restrict__ sW) {
    int e = blockIdx.x * 256 + threadIdx.x;
    if (e >= E_EDGES) return;
    int dst = ei[E_EDGES + e];
    int pos = atomicAdd(&cursor[dst], 1);
    sSrc[pos] = ei[e];
    sW[pos] = ew[e];
}

// ---------------------------------------------------------------------------
// agg[n,:] = sum_{e in CSR row n} w[e] * m[src[e],:]
// 32 lanes per node (4 feats each), 8 nodes per 256-block. No fp atomics.
// ---------------------------------------------------------------------------
__global__ __launch_bounds__(256) void gather_agg(const float* __restrict__ m,
                                                  const int* __restrict__ rowptr,
                                                  const int* __restrict__ sSrc,
                                                  const float* __restrict__ sW,
                                                  float* __restrict__ agg) {
    int t = blockIdx.x * 256 + threadIdx.x;
    int node = t >> 5;
    if (node >= N_NODES) return;
    int f0 = (t & 31) << 2;
    int e0 = rowptr[node], e1 = rowptr[node + 1];
    float4 acc = make_float4(0.f, 0.f, 0.f, 0.f);
    for (int e = e0; e < e1; ++e) {
        int s = sSrc[e];
        float w = sW[e];
        float4 v = *(const float4*)(m + (size_t)s * KD + f0);
        acc.x += w * v.x; acc.y += w * v.y;
        acc.z += w * v.z; acc.w += w * v.w;
    }
    *(float4*)(agg + (size_t)node * KD + f0) = acc;
}

// ---------------------------------------------------------------------------
// Generic fp32 GEMM (64x64 tile, 4x4/thread, k-major LDS tiles)
// ---------------------------------------------------------------------------
template <bool ACCUM, bool RELUA>
__global__ __launch_bounds__(256) void gemm_tn(const float* __restrict__ A,
                                               const float* __restrict__ W,
                                               const float* __restrict__ bias,
                                               float* __restrict__ out,
                                               int M, int ldo, int ocol0) {
    __shared__ float As[KD][68];
    __shared__ float Ws[KD][68];
    const int tid = threadIdx.x;
    const int row0 = blockIdx.x * 64;
    const int jc0 = blockIdx.y * 64;

#pragma unroll
    for (int i = 0; i < 8; ++i) {
        int f4 = tid + i * 256;
        int r = f4 >> 5;
        int c4 = (f4 & 31) << 2;
        int gr = row0 + r;
        float4 v = make_float4(0.f, 0.f, 0.f, 0.f);
        if (gr < M) v = *(const float4*)(A + (size_t)gr * KD + c4);
        if (RELUA) {
            v.x = fmaxf(v.x, 0.f); v.y = fmaxf(v.y, 0.f);
            v.z = fmaxf(v.z, 0.f); v.w = fmaxf(v.w, 0.f);
        }
        As[c4 + 0][r] = v.x; As[c4 + 1][r] = v.y;
        As[c4 + 2][r] = v.z; As[c4 + 3][r] = v.w;
    }
#pragma unroll
    for (int i = 0; i < 8; ++i) {
        int f4 = tid + i * 256;
        int r = f4 >> 5;
        int c4 = (f4 & 31) << 2;
        float4 v = *(const float4*)(W + (size_t)(jc0 + r) * KD + c4);
        Ws[c4 + 0][r] = v.x; Ws[c4 + 1][r] = v.y;
        Ws[c4 + 2][r] = v.z; Ws[c4 + 3][r] = v.w;
    }
    __syncthreads();

    const int tx4 = (tid & 15) << 2;
    const int ty4 = (tid >> 4) << 2;
    float acc[4][4] = {};
#pragma unroll 8
    for (int k = 0; k < KD; ++k) {
        float4 av = *(const float4*)&As[k][ty4];
        float4 wv = *(const float4*)&Ws[k][tx4];
        acc[0][0] += av.x * wv.x; acc[0][1] += av.x * wv.y;
        acc[0][2] += av.x * wv.z; acc[0][3] += av.x * wv.w;
        acc[1][0] += av.y * wv.x; acc[1][1] += av.y * wv.y;
        acc[1][2] += av.y * wv.z; acc[1][3] += av.y * wv.w;
        acc[2][0] += av.z * wv.x; acc[2][1] += av.z * wv.y;
        acc[2][2] += av.z * wv.z; acc[2][3] += av.z * wv.w;
        acc[3][0] += av.w * wv.x; acc[3][1] += av.w * wv.y;
        acc[3][2] += av.w * wv.z; acc[3][3] += av.w * wv.w;
    }

#pragma unroll
    for (int i = 0; i < 4; ++i) {
        int gr = row0 + ty4 + i;
        if (gr >= M) continue;
        float* op = out + (size_t)gr * ldo + ocol0 + jc0 + tx4;
#pragma unroll
        for (int j = 0; j < 4; ++j) {
            float v = acc[i][j];
            if (bias) v += bias[jc0 + tx4 + j];
            if (ACCUM) op[j] += v; else op[j] = v;
        }
    }
}

// ---------------------------------------------------------------------------
// GRU / LSTM elementwise
// ---------------------------------------------------------------------------
__global__ __launch_bounds__(256) void gru_elem(const float* __restrict__ G,
                                                const float* __restrict__ hin,
                                                float* __restrict__ hout) {
    int t = blockIdx.x * 256 + threadIdx.x;
    if (t >= N_NODES * KD) return;
    int n = t >> 7;
    int j = t & 127;
    const float* g = G + (size_t)n * 512;
    float r = sigmoidf_(g[j]);
    float z = sigmoidf_(g[128 + j]);
    float nc = tanhf(g[256 + j] + r * g[384 + j]);
    hout[t] = (1.f - z) * nc + z * hin[t];
}

__global__ __launch_bounds__(256) void lstm_elem(const float* __restrict__ G,
                                                 const float* __restrict__ C,
                                                 float* __restrict__ hout,
                                                 float* __restrict__ cout) {
    int t = blockIdx.x * 256 + threadIdx.x;
    if (t >= N_NODES * KD) return;
    int n = t >> 7;
    int j = t & 127;
    const float* g = G + (size_t)n * 512;
    float ig = sigmoidf_(g[j]);
    float fg = sigmoidf_(g[128 + j]);
    float gg = tanhf(g[256 + j]);
    float og = sigmoidf_(g[384 + j]);
    float c = fg * C[t] + ig * gg;
    hout[t] = og * tanhf(c);
    cout[t] = c;
}

extern "C" void kernel_launch(void* const* d_in, const int* in_sizes, int n_in,
                              void* d_out, int out_size, void* d_ws, size_t ws_size,
                              hipStream_t stream) {
    const float* x        = (const float*)d_in[0];
    const int*   ei       = (const int*)d_in[1];
    const float* ew       = (const float*)d_in[2];
    const float* H        = (const float*)d_in[3];
    const float* C        = (const float*)d_in[4];
    const float* ggc_w    = (const float*)d_in[5];
    const float* gru_wih  = (const float*)d_in[6];
    const float* gru_whh  = (const float*)d_in[7];
    const float* gru_bih  = (const float*)d_in[8];
    const float* gru_bhh  = (const float*)d_in[9];
    const float* lstm_wih = (const float*)d_in[10];
    const float* lstm_whh = (const float*)d_in[11];
    const float* lstm_bih = (const float*)d_in[12];
    const float* lstm_bhh = (const float*)d_in[13];
    const float* lin_w    = (const float*)d_in[14];
    const float* lin_b    = (const float*)d_in[15];

    float* out_head = (float*)d_out;                   // [N][64]
    float* hbuf = out_head + (size_t)N_NODES * 64;     // h_new region [N][128]
    float* mbuf = hbuf + (size_t)N_NODES * KD;         // c_new region [N][128]

    // workspace layout
    float* agg    = (float*)d_ws;                      // [N][128]
    float* G      = agg + (size_t)N_NODES * KD;        // [N][512]
    float* wgT    = G + (size_t)N_NODES * 512;         // [2][128][128]
    int*   rowptr = (int*)(wgT + 2 * KD * KD);         // [N+1]
    int*   cursor = rowptr + 50304;                    // [N] (deg, then fill cursor)
    int*   sSrc   = cursor + 50304;                    // [E]
    float* sW     = (float*)(sSrc + E_EDGES);          // [E]

    dim3 blk(256);
    const int MT = (N_NODES + 63) / 64;
    const int EB = (E_EDGES + 255) / 256;

    transpose_wg<<<128, blk, 0, stream>>>(ggc_w, wgT);

    // --- CSR build (once; graph is layer-invariant) ---
    hipMemsetAsync(cursor, 0, N_NODES * sizeof(int), stream);
    count_deg<<<EB, blk, 0, stream>>>(ei, cursor);
    scan_deg<<<1, 1024, 0, stream>>>(cursor, rowptr);
    fill_csr<<<EB, blk, 0, stream>>>(ei, ew, cursor, sSrc, sW);

    const float* hcur = x;
    for (int layer = 0; layer < 2; ++layer) {
        gemm_tn<false, false><<<dim3(MT, 2), blk, 0, stream>>>(
            hcur, wgT + (size_t)layer * KD * KD, nullptr, mbuf, N_NODES, KD, 0);
        gather_agg<<<(N_NODES * 32 + 255) / 256, blk, 0, stream>>>(
            mbuf, rowptr, sSrc, sW, agg);
        gemm_tn<false, false><<<dim3(MT, 6), blk, 0, stream>>>(
            agg, gru_wih, gru_bih, G, N_NODES, 512, 0);
        gemm_tn<true, false><<<dim3(MT, 4), blk, 0, stream>>>(
            hcur, gru_whh, gru_bhh, G, N_NODES, 512, 0);
        gemm_tn<false, false><<<dim3(MT, 2), blk, 0, stream>>>(
            hcur, gru_whh + 256 * KD, gru_bhh + 256, G, N_NODES, 512, 384);
        gru_elem<<<(N_NODES * KD + 255) / 256, blk, 0, stream>>>(G, hcur, hbuf);
        hcur = hbuf;
    }

    gemm_tn<false, false><<<dim3(MT, 8), blk, 0, stream>>>(
        hbuf, lstm_wih, lstm_bih, G, N_NODES, 512, 0);
    gemm_tn<true, false><<<dim3(MT, 8), blk, 0, stream>>>(
        H, lstm_whh, lstm_bhh, G, N_NODES, 512, 0);
    lstm_elem<<<(N_NODES * KD + 255) / 256, blk, 0, stream>>>(G, C, hbuf, mbuf);

    gemm_tn<false, true><<<dim3(MT, 1), blk, 0, stream>>>(
        hbuf, lin_w, lin_b, out_head, N_NODES, 64, 0);
}

// Round 3
// 714.175 us; speedup vs baseline: 5.4067x; 2.0406x over previous
//
#include <hip/hip_runtime.h>
#include <math.h>

#define N_NODES 50000
#define E_EDGES 800000
#define KD 128

typedef __attribute__((ext_vector_type(8))) short bf16x8;
typedef __attribute__((ext_vector_type(4))) float f32x4;

__device__ __forceinline__ float sigmoidf_(float x) { return 1.f / (1.f + expf(-x)); }

__device__ __forceinline__ unsigned short f2bf(float f) {
    unsigned u = __float_as_uint(f);
    return (unsigned short)((u + 0x7FFFu + ((u >> 16) & 1u)) >> 16);
}
__device__ __forceinline__ float bf2f(unsigned short b) {
    return __uint_as_float(((unsigned)b) << 16);
}
__device__ __forceinline__ bf16x8 ldfrag(const unsigned short* p) {
    return *(const bf16x8*)(const void*)p;
}

// ---------------------------------------------------------------------------
// fp32 -> bf16 convert (vectorized), n4 = elem_count/4
// ---------------------------------------------------------------------------
__global__ __launch_bounds__(256) void cvt_bf16(const float* __restrict__ in,
                                                unsigned short* __restrict__ out, int n4) {
    int t = blockIdx.x * 256 + threadIdx.x;
    if (t >= n4) return;
    float4 v = ((const float4*)in)[t];
    ushort4 o;
    o.x = f2bf(v.x); o.y = f2bf(v.y); o.z = f2bf(v.z); o.w = f2bf(v.w);
    ((ushort4*)out)[t] = o;
}

// Transpose+convert GGC weights [2][128][128]: WT[l][c][r] = W[l][r][c]
__global__ __launch_bounds__(256) void transpose_wg_bf16(const float* __restrict__ W,
                                                         unsigned short* __restrict__ WT) {
    int t = blockIdx.x * 256 + threadIdx.x;   // 32768
    int l = t >> 14;
    int r = (t >> 7) & 127;
    int c = t & 127;
    WT[l * 16384 + c * 128 + r] = f2bf(W[l * 16384 + r * 128 + c]);
}

// ---------------------------------------------------------------------------
// CSR build (degree -> scan -> fill)
// ---------------------------------------------------------------------------
__global__ __launch_bounds__(256) void count_deg(const int* __restrict__ ei,
                                                 int* __restrict__ deg) {
    int e = blockIdx.x * 256 + threadIdx.x;
    if (e >= E_EDGES) return;
    atomicAdd(&deg[ei[E_EDGES + e]], 1);
}

#define SCAN_CHUNK 49
__global__ __launch_bounds__(1024) void scan_deg(int* __restrict__ cursor,
                                                 int* __restrict__ rowptr) {
    __shared__ int part[1024];
    const int t = threadIdx.x;
    const int base = t * SCAN_CHUNK;
    int sum = 0;
    for (int i = 0; i < SCAN_CHUNK; ++i) {
        int idx = base + i;
        if (idx < N_NODES) sum += cursor[idx];
    }
    part[t] = sum;
    __syncthreads();
    for (int off = 1; off < 1024; off <<= 1) {
        int v = (t >= off) ? part[t - off] : 0;
        __syncthreads();
        part[t] += v;
        __syncthreads();
    }
    int running = part[t] - sum;
    for (int i = 0; i < SCAN_CHUNK; ++i) {
        int idx = base + i;
        if (idx < N_NODES) {
            int d = cursor[idx];
            rowptr[idx] = running;
            cursor[idx] = running;
            running += d;
        }
    }
    if (t == 1023) rowptr[N_NODES] = part[1023];
}

__global__ __launch_bounds__(256) void fill_csr(const int* __restrict__ ei,
                                                const float* __restrict__ ew,
                                                int* __restrict__ cursor,
                                                int* __restrict__ sSrc,
                                                float* __restrict__ sW) {
    int e = blockIdx.x * 256 + threadIdx.x;
    if (e >= E_EDGES) return;
    int dst = ei[E_EDGES + e];
    int pos = atomicAdd(&cursor[dst], 1);
    sSrc[pos] = ei[e];
    sW[pos] = ew[e];
}

// ---------------------------------------------------------------------------
// m = h @ Wg  (bf16 MFMA). A:[N][128] bf16, WT:[128 j][128 k] bf16, out bf16.
// 4 waves/block, wave w = rows blockIdx*64 + w*16; loops 8 j-tiles.
// ---------------------------------------------------------------------------
__global__ __launch_bounds__(256) void mfma_gemm_m(const unsigned short* __restrict__ A,
                                                   const unsigned short* __restrict__ WT,
                                                   unsigned short* __restrict__ Mout) {
    const int lane = threadIdx.x & 63, wave = threadIdx.x >> 6;
    const int row0 = blockIdx.x * 64 + wave * 16;
    const int rl = lane & 15, kg = lane >> 4;
    const size_t arow = (size_t)min(row0 + rl, N_NODES - 1);
    bf16x8 a[4];
#pragma unroll
    for (int kk = 0; kk < 4; ++kk)
        a[kk] = ldfrag(A + arow * KD + kk * 32 + kg * 8);
#pragma unroll
    for (int jt = 0; jt < 8; ++jt) {
        f32x4 acc = {0.f, 0.f, 0.f, 0.f};
        const unsigned short* wrow = WT + (size_t)(jt * 16 + rl) * KD + kg * 8;
#pragma unroll
        for (int kk = 0; kk < 4; ++kk)
            acc = __builtin_amdgcn_mfma_f32_16x16x32_bf16(a[kk], ldfrag(wrow + kk * 32), acc, 0, 0, 0);
        int col = jt * 16 + rl;
#pragma unroll
        for (int p = 0; p < 4; ++p) {
            int row = row0 + kg * 4 + p;
            if (row < N_NODES) Mout[(size_t)row * KD + col] = f2bf(acc[p]);
        }
    }
}

// ---------------------------------------------------------------------------
// agg[n,:] = sum_e w[e]*m[src[e],:]  (bf16 in/out, fp32 accum, no fp atomics)
// ---------------------------------------------------------------------------
__global__ __launch_bounds__(256) void gather_agg_bf16(const unsigned short* __restrict__ m,
                                                       const int* __restrict__ rowptr,
                                                       const int* __restrict__ sSrc,
                                                       const float* __restrict__ sW,
                                                       unsigned short* __restrict__ agg) {
    int t = blockIdx.x * 256 + threadIdx.x;
    int node = t >> 5;
    if (node >= N_NODES) return;
    int f0 = (t & 31) << 2;
    int e0 = rowptr[node], e1 = rowptr[node + 1];
    float ax = 0.f, ay = 0.f, az = 0.f, aw = 0.f;
    for (int e = e0; e < e1; ++e) {
        int s = sSrc[e];
        float w = sW[e];
        ushort4 v = *(const ushort4*)(m + (size_t)s * KD + f0);
        ax += w * bf2f(v.x); ay += w * bf2f(v.y);
        az += w * bf2f(v.z); aw += w * bf2f(v.w);
    }
    ushort4 o;
    o.x = f2bf(ax); o.y = f2bf(ay); o.z = f2bf(az); o.w = f2bf(aw);
    *(ushort4*)(agg + (size_t)node * KD + f0) = o;
}

// ---------------------------------------------------------------------------
// Fused GRU cell: h = GRU(agg, h), in-place on bf16 h. Both matmuls + gates.
// Wih/Whh: [384][128] bf16 row-major (gate rows r:0-127, z:128-255, n:256-383)
// ---------------------------------------------------------------------------
__global__ __launch_bounds__(256) void gru_fused(const unsigned short* __restrict__ Agg,
                                                 unsigned short* __restrict__ Hh,
                                                 const unsigned short* __restrict__ Wih,
                                                 const unsigned short* __restrict__ Whh,
                                                 const float* __restrict__ bih,
                                                 const float* __restrict__ bhh) {
    const int lane = threadIdx.x & 63, wave = threadIdx.x >> 6;
    const int row0 = blockIdx.x * 64 + wave * 16;
    const int rl = lane & 15, kg = lane >> 4;
    const size_t arow = (size_t)min(row0 + rl, N_NODES - 1);
    bf16x8 a1[4], a2[4];
#pragma unroll
    for (int kk = 0; kk < 4; ++kk) {
        a1[kk] = ldfrag(Agg + arow * KD + kk * 32 + kg * 8);
        a2[kk] = ldfrag(Hh + arow * KD + kk * 32 + kg * 8);
    }
#pragma unroll
    for (int jt = 0; jt < 8; ++jt) {
        f32x4 ir = {0.f,0.f,0.f,0.f}, iz = ir, in_ = ir, hr = ir, hz = ir, hn = ir;
        const unsigned short* wr = Wih + (size_t)(jt * 16 + rl) * KD + kg * 8;
        const unsigned short* vr = Whh + (size_t)(jt * 16 + rl) * KD + kg * 8;
#pragma unroll
        for (int kk = 0; kk < 4; ++kk) {
            ir  = __builtin_amdgcn_mfma_f32_16x16x32_bf16(a1[kk], ldfrag(wr + kk * 32),             ir,  0, 0, 0);
            iz  = __builtin_amdgcn_mfma_f32_16x16x32_bf16(a1[kk], ldfrag(wr + 128 * KD + kk * 32),  iz,  0, 0, 0);
            in_ = __builtin_amdgcn_mfma_f32_16x16x32_bf16(a1[kk], ldfrag(wr + 256 * KD + kk * 32),  in_, 0, 0, 0);
            hr  = __builtin_amdgcn_mfma_f32_16x16x32_bf16(a2[kk], ldfrag(vr + kk * 32),             hr,  0, 0, 0);
            hz  = __builtin_amdgcn_mfma_f32_16x16x32_bf16(a2[kk], ldfrag(vr + 128 * KD + kk * 32),  hz,  0, 0, 0);
            hn  = __builtin_amdgcn_mfma_f32_16x16x32_bf16(a2[kk], ldfrag(vr + 256 * KD + kk * 32),  hn,  0, 0, 0);
        }
        const int col = jt * 16 + rl;
        const float b_ir = bih[col], b_iz = bih[128 + col], b_in = bih[256 + col];
        const float b_hr = bhh[col], b_hz = bhh[128 + col], b_hn = bhh[256 + col];
#pragma unroll
        for (int p = 0; p < 4; ++p) {
            int row = row0 + kg * 4 + p;
            if (row >= N_NODES) continue;
            float r = sigmoidf_(ir[p] + b_ir + hr[p] + b_hr);
            float z = sigmoidf_(iz[p] + b_iz + hz[p] + b_hz);
            float nc = tanhf(in_[p] + b_in + r * (hn[p] + b_hn));
            float hv = bf2f(Hh[(size_t)row * KD + col]);
            Hh[(size_t)row * KD + col] = f2bf((1.f - z) * nc + z * hv);
        }
    }
}

// ---------------------------------------------------------------------------
// Fused LSTM cell (single step): gates = h@Wihᵀ + hx@Whhᵀ + biases.
// Writes h_new fp32, c_new fp32 (d_out regions) and relu(h_new) bf16 in-place
// into Hh for the head GEMM. Wih/Whh: [512][128] bf16 (i,f,g,o).
// ---------------------------------------------------------------------------
__global__ __launch_bounds__(256) void lstm_fused(unsigned short* __restrict__ Hh,
                                                  const unsigned short* __restrict__ Hx,
                                                  const float* __restrict__ Cx,
                                                  const unsigned short* __restrict__ Wih,
                                                  const unsigned short* __restrict__ Whh,
                                                  const float* __restrict__ bih,
                                                  const float* __restrict__ bhh,
                                                  float* __restrict__ h_out,
                                                  float* __restrict__ c_out) {
    const int lane = threadIdx.x & 63, wave = threadIdx.x >> 6;
    const int row0 = blockIdx.x * 64 + wave * 16;
    const int rl = lane & 15, kg = lane >> 4;
    const size_t arow = (size_t)min(row0 + rl, N_NODES - 1);
    bf16x8 a1[4], a2[4];
#pragma unroll
    for (int kk = 0; kk < 4; ++kk) {
        a1[kk] = ldfrag(Hh + arow * KD + kk * 32 + kg * 8);
        a2[kk] = ldfrag(Hx + arow * KD + kk * 32 + kg * 8);
    }
#pragma unroll
    for (int jt = 0; jt < 8; ++jt) {
        f32x4 gi = {0.f,0.f,0.f,0.f}, gf = gi, gg = gi, go = gi;
        f32x4 hi = gi, hf = gi, hg = gi, ho = gi;
        const unsigned short* wr = Wih + (size_t)(jt * 16 + rl) * KD + kg * 8;
        const unsigned short* vr = Whh + (size_t)(jt * 16 + rl) * KD + kg * 8;
#pragma unroll
        for (int kk = 0; kk < 4; ++kk) {
            gi = __builtin_amdgcn_mfma_f32_16x16x32_bf16(a1[kk], ldfrag(wr + kk * 32),            gi, 0, 0, 0);
            gf = __builtin_amdgcn_mfma_f32_16x16x32_bf16(a1[kk], ldfrag(wr + 128 * KD + kk * 32), gf, 0, 0, 0);
            gg = __builtin_amdgcn_mfma_f32_16x16x32_bf16(a1[kk], ldfrag(wr + 256 * KD + kk * 32), gg, 0, 0, 0);
            go = __builtin_amdgcn_mfma_f32_16x16x32_bf16(a1[kk], ldfrag(wr + 384 * KD + kk * 32), go, 0, 0, 0);
            hi = __builtin_amdgcn_mfma_f32_16x16x32_bf16(a2[kk], ldfrag(vr + kk * 32),            hi, 0, 0, 0);
            hf = __builtin_amdgcn_mfma_f32_16x16x32_bf16(a2[kk], ldfrag(vr + 128 * KD + kk * 32), hf, 0, 0, 0);
            hg = __builtin_amdgcn_mfma_f32_16x16x32_bf16(a2[kk], ldfrag(vr + 256 * KD + kk * 32), hg, 0, 0, 0);
            ho = __builtin_amdgcn_mfma_f32_16x16x32_bf16(a2[kk], ldfrag(vr + 384 * KD + kk * 32), ho, 0, 0, 0);
        }
        const int col = jt * 16 + rl;
        const float b_i = bih[col] + bhh[col];
        const float b_f = bih[128 + col] + bhh[128 + col];
        const float b_g = bih[256 + col] + bhh[256 + col];
        const float b_o = bih[384 + col] + bhh[384 + col];
#pragma unroll
        for (int p = 0; p < 4; ++p) {
            int row = row0 + kg * 4 + p;
            if (row >= N_NODES) continue;
            float ig = sigmoidf_(gi[p] + hi[p] + b_i);
            float fg = sigmoidf_(gf[p] + hf[p] + b_f);
            float gv = tanhf(gg[p] + hg[p] + b_g);
            float og = sigmoidf_(go[p] + ho[p] + b_o);
            float c = fg * Cx[(size_t)row * KD + col] + ig * gv;
            float hn = og * tanhf(c);
            size_t idx = (size_t)row * KD + col;
            c_out[idx] = c;
            h_out[idx] = hn;
            Hh[idx] = f2bf(fmaxf(hn, 0.f));
        }
    }
}

// ---------------------------------------------------------------------------
// head: out[N][64] = hrelu @ lin_wᵀ + lin_b   (lin_w [64][128] bf16)
// ---------------------------------------------------------------------------
__global__ __launch_bounds__(256) void head_gemm(const unsigned short* __restrict__ Hr,
                                                 const unsigned short* __restrict__ LinW,
                                                 const float* __restrict__ lin_b,
                                                 float* __restrict__ Out) {
    const int lane = threadIdx.x & 63, wave = threadIdx.x >> 6;
    const int row0 = blockIdx.x * 64 + wave * 16;
    const int rl = lane & 15, kg = lane >> 4;
    const size_t arow = (size_t)min(row0 + rl, N_NODES - 1);
    bf16x8 a[4];
#pragma unroll
    for (int kk = 0; kk < 4; ++kk)
        a[kk] = ldfrag(Hr + arow * KD + kk * 32 + kg * 8);
#pragma unroll
    for (int jt = 0; jt < 4; ++jt) {
        f32x4 acc = {0.f, 0.f, 0.f, 0.f};
        const unsigned short* wrow = LinW + (size_t)(jt * 16 + rl) * KD + kg * 8;
#pragma unroll
        for (int kk = 0; kk < 4; ++kk)
            acc = __builtin_amdgcn_mfma_f32_16x16x32_bf16(a[kk], ldfrag(wrow + kk * 32), acc, 0, 0, 0);
        int col = jt * 16 + rl;
        float b = lin_b[col];
#pragma unroll
        for (int p = 0; p < 4; ++p) {
            int row = row0 + kg * 4 + p;
            if (row < N_NODES) Out[(size_t)row * 64 + col] = acc[p] + b;
        }
    }
}

extern "C" void kernel_launch(void* const* d_in, const int* in_sizes, int n_in,
                              void* d_out, int out_size, void* d_ws, size_t ws_size,
                              hipStream_t stream) {
    const float* x        = (const float*)d_in[0];
    const int*   ei       = (const int*)d_in[1];
    const float* ew       = (const float*)d_in[2];
    const float* H        = (const float*)d_in[3];
    const float* C        = (const float*)d_in[4];
    const float* ggc_w    = (const float*)d_in[5];
    const float* gru_wih  = (const float*)d_in[6];
    const float* gru_whh  = (const float*)d_in[7];
    const float* gru_bih  = (const float*)d_in[8];
    const float* gru_bhh  = (const float*)d_in[9];
    const float* lstm_wih = (const float*)d_in[10];
    const float* lstm_whh = (const float*)d_in[11];
    const float* lstm_bih = (const float*)d_in[12];
    const float* lstm_bhh = (const float*)d_in[13];
    const float* lin_w    = (const float*)d_in[14];
    const float* lin_b    = (const float*)d_in[15];

    float* out_head = (float*)d_out;                   // [N][64]
    float* h_out = out_head + (size_t)N_NODES * 64;    // h_new [N][128]
    float* c_out = h_out + (size_t)N_NODES * KD;       // c_new [N][128]

    // workspace layout (all 256B-aligned sizes)
    char* w = (char*)d_ws;
    unsigned short* hb    = (unsigned short*)w; w += (size_t)N_NODES * KD * 2;   // h bf16
    unsigned short* Hxb   = (unsigned short*)w; w += (size_t)N_NODES * KD * 2;   // H bf16
    unsigned short* mb    = (unsigned short*)w; w += (size_t)N_NODES * KD * 2;   // m bf16
    unsigned short* aggb  = (unsigned short*)w; w += (size_t)N_NODES * KD * 2;   // agg bf16
    unsigned short* wgTb  = (unsigned short*)w; w += 2 * KD * KD * 2;            // WgT bf16
    unsigned short* wihb  = (unsigned short*)w; w += 384 * KD * 2;
    unsigned short* whhb  = (unsigned short*)w; w += 384 * KD * 2;
    unsigned short* lwihb = (unsigned short*)w; w += 512 * KD * 2;
    unsigned short* lwhhb = (unsigned short*)w; w += 512 * KD * 2;
    unsigned short* linwb = (unsigned short*)w; w += 64 * KD * 2;
    int*   rowptr = (int*)w; w += 50304 * 4;
    int*   cursor = (int*)w; w += 50304 * 4;
    int*   sSrc   = (int*)w; w += (size_t)E_EDGES * 4;
    float* sW     = (float*)w; w += (size_t)E_EDGES * 4;

    dim3 blk(256);
    const int MB = (N_NODES + 63) / 64;            // 782 row-tile blocks
    const int EB = (E_EDGES + 255) / 256;
    const int NF4 = N_NODES * KD / 4;              // 1.6M float4s

    // converts
    cvt_bf16<<<(NF4 + 255) / 256, blk, 0, stream>>>(x, hb, NF4);
    cvt_bf16<<<(NF4 + 255) / 256, blk, 0, stream>>>(H, Hxb, NF4);
    cvt_bf16<<<(384 * KD / 4 + 255) / 256, blk, 0, stream>>>(gru_wih, wihb, 384 * KD / 4);
    cvt_bf16<<<(384 * KD / 4 + 255) / 256, blk, 0, stream>>>(gru_whh, whhb, 384 * KD / 4);
    cvt_bf16<<<(512 * KD / 4 + 255) / 256, blk, 0, stream>>>(lstm_wih, lwihb, 512 * KD / 4);
    cvt_bf16<<<(512 * KD / 4 + 255) / 256, blk, 0, stream>>>(lstm_whh, lwhhb, 512 * KD / 4);
    cvt_bf16<<<(64 * KD / 4 + 255) / 256, blk, 0, stream>>>(lin_w, linwb, 64 * KD / 4);
    transpose_wg_bf16<<<128, blk, 0, stream>>>(ggc_w, wgTb);

    // CSR build
    hipMemsetAsync(cursor, 0, N_NODES * sizeof(int), stream);
    count_deg<<<EB, blk, 0, stream>>>(ei, cursor);
    scan_deg<<<1, 1024, 0, stream>>>(cursor, rowptr);
    fill_csr<<<EB, blk, 0, stream>>>(ei, ew, cursor, sSrc, sW);

    for (int layer = 0; layer < 2; ++layer) {
        mfma_gemm_m<<<MB, blk, 0, stream>>>(hb, wgTb + (size_t)layer * KD * KD, mb);
        gather_agg_bf16<<<(N_NODES * 32 + 255) / 256, blk, 0, stream>>>(
            mb, rowptr, sSrc, sW, aggb);
        gru_fused<<<MB, blk, 0, stream>>>(aggb, hb, wihb, whhb, gru_bih, gru_bhh);
    }

    lstm_fused<<<MB, blk, 0, stream>>>(hb, Hxb, C, lwihb, lwhhb,
                                       lstm_bih, lstm_bhh, h_out, c_out);
    head_gemm<<<MB, blk, 0, stream>>>(hb, linwb, lin_b, out_head);
}

// Round 4
// 548.389 us; speedup vs baseline: 7.0412x; 1.3023x over previous
//
#include <hip/hip_runtime.h>
#include <math.h>

#define N_NODES 50000
#define E_EDGES 800000
#define KD 128

typedef __attribute__((ext_vector_type(8))) short bf16x8;
typedef __attribute__((ext_vector_type(4))) float f32x4;

__device__ __forceinline__ float sigmoidf_(float x) { return 1.f / (1.f + expf(-x)); }

__device__ __forceinline__ unsigned short f2bf(float f) {
    unsigned u = __float_as_uint(f);
    return (unsigned short)((u + 0x7FFFu + ((u >> 16) & 1u)) >> 16);
}
__device__ __forceinline__ float bf2f(unsigned short b) {
    return __uint_as_float(((unsigned)b) << 16);
}
__device__ __forceinline__ bf16x8 ldfrag(const unsigned short* p) {
    return *(const bf16x8*)(const void*)p;
}
// DMA one 1KB fragment block: lane l's 16B from per-lane gsrc -> lds + l*16
__device__ __forceinline__ void stage_frag(const unsigned short* g, unsigned short* l) {
    __builtin_amdgcn_global_load_lds(
        (const __attribute__((address_space(1))) unsigned int*)g,
        (__attribute__((address_space(3))) unsigned int*)l, 16, 0, 0);
}

// ---------------------------------------------------------------------------
// fp32 -> bf16 converts
// ---------------------------------------------------------------------------
__global__ __launch_bounds__(256) void cvt_bf16(const float* __restrict__ in,
                                                unsigned short* __restrict__ out, int n4) {
    int t = blockIdx.x * 256 + threadIdx.x;
    if (t >= n4) return;
    float4 v = ((const float4*)in)[t];
    ushort4 o;
    o.x = f2bf(v.x); o.y = f2bf(v.y); o.z = f2bf(v.z); o.w = f2bf(v.w);
    ((ushort4*)out)[t] = o;
}

// all small weight matrices in one launch (float4 units)
__global__ __launch_bounds__(256) void cvt_weights(
        const float* __restrict__ a, const float* __restrict__ b,
        const float* __restrict__ c, const float* __restrict__ d,
        const float* __restrict__ e,
        unsigned short* __restrict__ oa, unsigned short* __restrict__ ob,
        unsigned short* __restrict__ oc, unsigned short* __restrict__ od,
        unsigned short* __restrict__ oe) {
    int t = blockIdx.x * 256 + threadIdx.x;
    const float* in; unsigned short* out; int idx;
    if      (t < 12288)  { in = a; out = oa; idx = t; }
    else if (t < 24576)  { in = b; out = ob; idx = t - 12288; }
    else if (t < 40960)  { in = c; out = oc; idx = t - 24576; }
    else if (t < 57344)  { in = d; out = od; idx = t - 40960; }
    else if (t < 59392)  { in = e; out = oe; idx = t - 57344; }
    else return;
    float4 v = ((const float4*)in)[idx];
    ushort4 o;
    o.x = f2bf(v.x); o.y = f2bf(v.y); o.z = f2bf(v.z); o.w = f2bf(v.w);
    ((ushort4*)out)[idx] = o;
}

// Transpose+convert GGC weights [2][128][128]: WT[l][c][r] = W[l][r][c]
__global__ __launch_bounds__(256) void transpose_wg_bf16(const float* __restrict__ W,
                                                         unsigned short* __restrict__ WT) {
    int t = blockIdx.x * 256 + threadIdx.x;
    int l = t >> 14;
    int r = (t >> 7) & 127;
    int c = t & 127;
    WT[l * 16384 + c * 128 + r] = f2bf(W[l * 16384 + r * 128 + c]);
}

// ---------------------------------------------------------------------------
// CSR build
// ---------------------------------------------------------------------------
__global__ __launch_bounds__(256) void count_deg(const int* __restrict__ ei,
                                                 int* __restrict__ deg) {
    int e = blockIdx.x * 256 + threadIdx.x;
    if (e >= E_EDGES) return;
    atomicAdd(&deg[ei[E_EDGES + e]], 1);
}

#define SCAN_CHUNK 49
__global__ __launch_bounds__(1024) void scan_deg(int* __restrict__ cursor,
                                                 int* __restrict__ rowptr) {
    __shared__ int part[1024];
    const int t = threadIdx.x;
    const int base = t * SCAN_CHUNK;
    int sum = 0;
    for (int i = 0; i < SCAN_CHUNK; ++i) {
        int idx = base + i;
        if (idx < N_NODES) sum += cursor[idx];
    }
    part[t] = sum;
    __syncthreads();
    for (int off = 1; off < 1024; off <<= 1) {
        int v = (t >= off) ? part[t - off] : 0;
        __syncthreads();
        part[t] += v;
        __syncthreads();
    }
    int running = part[t] - sum;
    for (int i = 0; i < SCAN_CHUNK; ++i) {
        int idx = base + i;
        if (idx < N_NODES) {
            int d = cursor[idx];
            rowptr[idx] = running;
            cursor[idx] = running;
            running += d;
        }
    }
    if (t == 1023) rowptr[N_NODES] = part[1023];
}

__global__ __launch_bounds__(256) void fill_csr(const int* __restrict__ ei,
                                                const float* __restrict__ ew,
                                                int* __restrict__ cursor,
                                                int* __restrict__ sSrc,
                                                float* __restrict__ sW) {
    int e = blockIdx.x * 256 + threadIdx.x;
    if (e >= E_EDGES) return;
    int dst = ei[E_EDGES + e];
    int pos = atomicAdd(&cursor[dst], 1);
    sSrc[pos] = ei[e];
    sW[pos] = ew[e];
}

// ---------------------------------------------------------------------------
// agg[n,:] = sum_e w[e]*m[src[e],:]  (bf16, fp32 accum)
// ---------------------------------------------------------------------------
__global__ __launch_bounds__(256) void gather_agg_bf16(const unsigned short* __restrict__ m,
                                                       const int* __restrict__ rowptr,
                                                       const int* __restrict__ sSrc,
                                                       const float* __restrict__ sW,
                                                       unsigned short* __restrict__ agg) {
    int t = blockIdx.x * 256 + threadIdx.x;
    int node = t >> 5;
    if (node >= N_NODES) return;
    int f0 = (t & 31) << 2;
    int e0 = rowptr[node], e1 = rowptr[node + 1];
    float ax = 0.f, ay = 0.f, az = 0.f, aw = 0.f;
    for (int e = e0; e < e1; ++e) {
        int s = sSrc[e];
        float w = sW[e];
        ushort4 v = *(const ushort4*)(m + (size_t)s * KD + f0);
        ax += w * bf2f(v.x); ay += w * bf2f(v.y);
        az += w * bf2f(v.z); aw += w * bf2f(v.w);
    }
    ushort4 o;
    o.x = f2bf(ax); o.y = f2bf(ay); o.z = f2bf(az); o.w = f2bf(aw);
    *(ushort4*)(agg + (size_t)node * KD + f0) = o;
}

// ---------------------------------------------------------------------------
// m = h @ Wg. Weights (32 KB) staged ONCE in LDS, fragment-packed.
// ---------------------------------------------------------------------------
__global__ __launch_bounds__(256) void mfma_gemm_m(const unsigned short* __restrict__ A,
                                                   const unsigned short* __restrict__ WT,
                                                   unsigned short* __restrict__ Mout) {
    __shared__ unsigned short wlds[32 * 512];   // 32 frag-blocks x 1KB
    const int lane = threadIdx.x & 63, wave = threadIdx.x >> 6;
    const int row0 = blockIdx.x * 64 + wave * 16;
    const int rl = lane & 15, kg = lane >> 4;
    for (int f = wave; f < 32; f += 4) {
        int jt = f >> 2, kk = f & 3;
        stage_frag(WT + (size_t)(jt * 16 + rl) * KD + kk * 32 + kg * 8, wlds + f * 512);
    }
    const size_t arow = (size_t)min(row0 + rl, N_NODES - 1);
    bf16x8 a[4];
#pragma unroll
    for (int kk = 0; kk < 4; ++kk)
        a[kk] = ldfrag(A + arow * KD + kk * 32 + kg * 8);
    __syncthreads();
#pragma unroll
    for (int jt = 0; jt < 8; ++jt) {
        f32x4 acc = {0.f, 0.f, 0.f, 0.f};
#pragma unroll
        for (int kk = 0; kk < 4; ++kk)
            acc = __builtin_amdgcn_mfma_f32_16x16x32_bf16(
                a[kk], ldfrag(wlds + (jt * 4 + kk) * 512 + lane * 8), acc, 0, 0, 0);
        int col = jt * 16 + rl;
#pragma unroll
        for (int p = 0; p < 4; ++p) {
            int row = row0 + kg * 4 + p;
            if (row < N_NODES) Mout[(size_t)row * KD + col] = f2bf(acc[p]);
        }
    }
}

// ---------------------------------------------------------------------------
// Fused GRU cell, double-buffered LDS weight tiles (6 slices x 4 kk per jt)
// ---------------------------------------------------------------------------
__global__ __launch_bounds__(256) void gru_fused(const unsigned short* __restrict__ Agg,
                                                 unsigned short* __restrict__ Hh,
                                                 const unsigned short* __restrict__ Wih,
                                                 const unsigned short* __restrict__ Whh,
                                                 const float* __restrict__ bih,
                                                 const float* __restrict__ bhh) {
    __shared__ unsigned short lds[2 * 24 * 512];   // 48 KB
    const int lane = threadIdx.x & 63, wave = threadIdx.x >> 6;
    const int row0 = blockIdx.x * 64 + wave * 16;
    const int rl = lane & 15, kg = lane >> 4;

    auto stage = [&](int jt, int buf) {
        unsigned short* b = lds + buf * 24 * 512;
        for (int q = wave; q < 24; q += 4) {
            int s = q >> 2, kk = q & 3;
            const unsigned short* src = (s < 3 ? Wih + (size_t)s * 128 * KD
                                               : Whh + (size_t)(s - 3) * 128 * KD)
                                        + (size_t)(jt * 16 + rl) * KD + kk * 32 + kg * 8;
            stage_frag(src, b + q * 512);
        }
    };

    stage(0, 0);
    const size_t arow = (size_t)min(row0 + rl, N_NODES - 1);
    bf16x8 a1[4], a2[4];
#pragma unroll
    for (int kk = 0; kk < 4; ++kk) {
        a1[kk] = ldfrag(Agg + arow * KD + kk * 32 + kg * 8);
        a2[kk] = ldfrag(Hh + arow * KD + kk * 32 + kg * 8);
    }
    __syncthreads();

    for (int jt = 0; jt < 8; ++jt) {
        const unsigned short* cw = lds + (jt & 1) * 24 * 512;
        if (jt < 7) stage(jt + 1, (jt + 1) & 1);
        f32x4 ir = {0.f,0.f,0.f,0.f}, iz = ir, in_ = ir, hr = ir, hz = ir, hn = ir;
#pragma unroll
        for (int kk = 0; kk < 4; ++kk) {
            ir  = __builtin_amdgcn_mfma_f32_16x16x32_bf16(a1[kk], ldfrag(cw + (0*4+kk)*512 + lane*8), ir,  0, 0, 0);
            iz  = __builtin_amdgcn_mfma_f32_16x16x32_bf16(a1[kk], ldfrag(cw + (1*4+kk)*512 + lane*8), iz,  0, 0, 0);
            in_ = __builtin_amdgcn_mfma_f32_16x16x32_bf16(a1[kk], ldfrag(cw + (2*4+kk)*512 + lane*8), in_, 0, 0, 0);
            hr  = __builtin_amdgcn_mfma_f32_16x16x32_bf16(a2[kk], ldfrag(cw + (3*4+kk)*512 + lane*8), hr,  0, 0, 0);
            hz  = __builtin_amdgcn_mfma_f32_16x16x32_bf16(a2[kk], ldfrag(cw + (4*4+kk)*512 + lane*8), hz,  0, 0, 0);
            hn  = __builtin_amdgcn_mfma_f32_16x16x32_bf16(a2[kk], ldfrag(cw + (5*4+kk)*512 + lane*8), hn,  0, 0, 0);
        }
        const int col = jt * 16 + rl;
        const float b_ir = bih[col], b_iz = bih[128 + col], b_in = bih[256 + col];
        const float b_hr = bhh[col], b_hz = bhh[128 + col], b_hn = bhh[256 + col];
#pragma unroll
        for (int p = 0; p < 4; ++p) {
            int row = row0 + kg * 4 + p;
            if (row >= N_NODES) continue;
            float r = sigmoidf_(ir[p] + b_ir + hr[p] + b_hr);
            float z = sigmoidf_(iz[p] + b_iz + hz[p] + b_hz);
            float nc = tanhf(in_[p] + b_in + r * (hn[p] + b_hn));
            float hv = bf2f(Hh[(size_t)row * KD + col]);
            Hh[(size_t)row * KD + col] = f2bf((1.f - z) * nc + z * hv);
        }
        __syncthreads();
    }
}

// ---------------------------------------------------------------------------
// Fused LSTM cell, double-buffered LDS weight tiles (8 slices x 4 kk per jt)
// ---------------------------------------------------------------------------
__global__ __launch_bounds__(256) void lstm_fused(unsigned short* __restrict__ Hh,
                                                  const unsigned short* __restrict__ Hx,
                                                  const float* __restrict__ Cx,
                                                  const unsigned short* __restrict__ Wih,
                                                  const unsigned short* __restrict__ Whh,
                                                  const float* __restrict__ bih,
                                                  const float* __restrict__ bhh,
                                                  float* __restrict__ h_out,
                                                  float* __restrict__ c_out) {
    __shared__ unsigned short lds[2 * 32 * 512];   // 64 KB
    const int lane = threadIdx.x & 63, wave = threadIdx.x >> 6;
    const int row0 = blockIdx.x * 64 + wave * 16;
    const int rl = lane & 15, kg = lane >> 4;

    auto stage = [&](int jt, int buf) {
        unsigned short* b = lds + buf * 32 * 512;
        for (int q = wave; q < 32; q += 4) {
            int s = q >> 2, kk = q & 3;
            const unsigned short* src = (s < 4 ? Wih + (size_t)s * 128 * KD
                                               : Whh + (size_t)(s - 4) * 128 * KD)
                                        + (size_t)(jt * 16 + rl) * KD + kk * 32 + kg * 8;
            stage_frag(src, b + q * 512);
        }
    };

    stage(0, 0);
    const size_t arow = (size_t)min(row0 + rl, N_NODES - 1);
    bf16x8 a1[4], a2[4];
#pragma unroll
    for (int kk = 0; kk < 4; ++kk) {
        a1[kk] = ldfrag(Hh + arow * KD + kk * 32 + kg * 8);
        a2[kk] = ldfrag(Hx + arow * KD + kk * 32 + kg * 8);
    }
    __syncthreads();

    for (int jt = 0; jt < 8; ++jt) {
        const unsigned short* cw = lds + (jt & 1) * 32 * 512;
        if (jt < 7) stage(jt + 1, (jt + 1) & 1);
        f32x4 gi = {0.f,0.f,0.f,0.f}, gf = gi, gg = gi, go = gi;
        f32x4 hi = gi, hf = gi, hg = gi, ho = gi;
#pragma unroll
        for (int kk = 0; kk < 4; ++kk) {
            gi = __builtin_amdgcn_mfma_f32_16x16x32_bf16(a1[kk], ldfrag(cw + (0*4+kk)*512 + lane*8), gi, 0, 0, 0);
            gf = __builtin_amdgcn_mfma_f32_16x16x32_bf16(a1[kk], ldfrag(cw + (1*4+kk)*512 + lane*8), gf, 0, 0, 0);
            gg = __builtin_amdgcn_mfma_f32_16x16x32_bf16(a1[kk], ldfrag(cw + (2*4+kk)*512 + lane*8), gg, 0, 0, 0);
            go = __builtin_amdgcn_mfma_f32_16x16x32_bf16(a1[kk], ldfrag(cw + (3*4+kk)*512 + lane*8), go, 0, 0, 0);
            hi = __builtin_amdgcn_mfma_f32_16x16x32_bf16(a2[kk], ldfrag(cw + (4*4+kk)*512 + lane*8), hi, 0, 0, 0);
            hf = __builtin_amdgcn_mfma_f32_16x16x32_bf16(a2[kk], ldfrag(cw + (5*4+kk)*512 + lane*8), hf, 0, 0, 0);
            hg = __builtin_amdgcn_mfma_f32_16x16x32_bf16(a2[kk], ldfrag(cw + (6*4+kk)*512 + lane*8), hg, 0, 0, 0);
            ho = __builtin_amdgcn_mfma_f32_16x16x32_bf16(a2[kk], ldfrag(cw + (7*4+kk)*512 + lane*8), ho, 0, 0, 0);
        }
        const int col = jt * 16 + rl;
        const float b_i = bih[col] + bhh[col];
        const float b_f = bih[128 + col] + bhh[128 + col];
        const float b_g = bih[256 + col] + bhh[256 + col];
        const float b_o = bih[384 + col] + bhh[384 + col];
#pragma unroll
        for (int p = 0; p < 4; ++p) {
            int row = row0 + kg * 4 + p;
            if (row >= N_NODES) continue;
            float ig = sigmoidf_(gi[p] + hi[p] + b_i);
            float fg = sigmoidf_(gf[p] + hf[p] + b_f);
            float gv = tanhf(gg[p] + hg[p] + b_g);
            float og = sigmoidf_(go[p] + ho[p] + b_o);
            float c = fg * Cx[(size_t)row * KD + col] + ig * gv;
            float hn = og * tanhf(c);
            size_t idx = (size_t)row * KD + col;
            c_out[idx] = c;
            h_out[idx] = hn;
            Hh[idx] = f2bf(fmaxf(hn, 0.f));
        }
        __syncthreads();
    }
}

// ---------------------------------------------------------------------------
// head: out[N][64] = hrelu @ lin_wᵀ + lin_b. Weights (16 KB) staged once.
// ---------------------------------------------------------------------------
__global__ __launch_bounds__(256) void head_gemm(const unsigned short* __restrict__ Hr,
                                                 const unsigned short* __restrict__ LinW,
                                                 const float* __restrict__ lin_b,
                                                 float* __restrict__ Out) {
    __shared__ unsigned short wlds[16 * 512];   // 16 KB
    const int lane = threadIdx.x & 63, wave = threadIdx.x >> 6;
    const int row0 = blockIdx.x * 64 + wave * 16;
    const int rl = lane & 15, kg = lane >> 4;
    for (int f = wave; f < 16; f += 4) {
        int jt = f >> 2, kk = f & 3;
        stage_frag(LinW + (size_t)(jt * 16 + rl) * KD + kk * 32 + kg * 8, wlds + f * 512);
    }
    const size_t arow = (size_t)min(row0 + rl, N_NODES - 1);
    bf16x8 a[4];
#pragma unroll
    for (int kk = 0; kk < 4; ++kk)
        a[kk] = ldfrag(Hr + arow * KD + kk * 32 + kg * 8);
    __syncthreads();
#pragma unroll
    for (int jt = 0; jt < 4; ++jt) {
        f32x4 acc = {0.f, 0.f, 0.f, 0.f};
#pragma unroll
        for (int kk = 0; kk < 4; ++kk)
            acc = __builtin_amdgcn_mfma_f32_16x16x32_bf16(
                a[kk], ldfrag(wlds + (jt * 4 + kk) * 512 + lane * 8), acc, 0, 0, 0);
        int col = jt * 16 + rl;
        float b = lin_b[col];
#pragma unroll
        for (int p = 0; p < 4; ++p) {
            int row = row0 + kg * 4 + p;
            if (row < N_NODES) Out[(size_t)row * 64 + col] = acc[p] + b;
        }
    }
}

extern "C" void kernel_launch(void* const* d_in, const int* in_sizes, int n_in,
                              void* d_out, int out_size, void* d_ws, size_t ws_size,
                              hipStream_t stream) {
    const float* x        = (const float*)d_in[0];
    const int*   ei       = (const int*)d_in[1];
    const float* ew       = (const float*)d_in[2];
    const float* H        = (const float*)d_in[3];
    const float* C        = (const float*)d_in[4];
    const float* ggc_w    = (const float*)d_in[5];
    const float* gru_wih  = (const float*)d_in[6];
    const float* gru_whh  = (const float*)d_in[7];
    const float* gru_bih  = (const float*)d_in[8];
    const float* gru_bhh  = (const float*)d_in[9];
    const float* lstm_wih = (const float*)d_in[10];
    const float* lstm_whh = (const float*)d_in[11];
    const float* lstm_bih = (const float*)d_in[12];
    const float* lstm_bhh = (const float*)d_in[13];
    const float* lin_w    = (const float*)d_in[14];
    const float* lin_b    = (const float*)d_in[15];

    float* out_head = (float*)d_out;                   // [N][64]
    float* h_out = out_head + (size_t)N_NODES * 64;    // h_new [N][128]
    float* c_out = h_out + (size_t)N_NODES * KD;       // c_new [N][128]

    char* w = (char*)d_ws;
    unsigned short* hb    = (unsigned short*)w; w += (size_t)N_NODES * KD * 2;
    unsigned short* Hxb   = (unsigned short*)w; w += (size_t)N_NODES * KD * 2;
    unsigned short* mb    = (unsigned short*)w; w += (size_t)N_NODES * KD * 2;
    unsigned short* aggb  = (unsigned short*)w; w += (size_t)N_NODES * KD * 2;
    unsigned short* wgTb  = (unsigned short*)w; w += 2 * KD * KD * 2;
    unsigned short* wihb  = (unsigned short*)w; w += 384 * KD * 2;
    unsigned short* whhb  = (unsigned short*)w; w += 384 * KD * 2;
    unsigned short* lwihb = (unsigned short*)w; w += 512 * KD * 2;
    unsigned short* lwhhb = (unsigned short*)w; w += 512 * KD * 2;
    unsigned short* linwb = (unsigned short*)w; w += 64 * KD * 2;
    int*   rowptr = (int*)w; w += 50304 * 4;
    int*   cursor = (int*)w; w += 50304 * 4;
    int*   sSrc   = (int*)w; w += (size_t)E_EDGES * 4;
    float* sW     = (float*)w; w += (size_t)E_EDGES * 4;

    dim3 blk(256);
    const int MB = (N_NODES + 63) / 64;
    const int EB = (E_EDGES + 255) / 256;
    const int NF4 = N_NODES * KD / 4;

    cvt_bf16<<<(NF4 + 255) / 256, blk, 0, stream>>>(x, hb, NF4);
    cvt_bf16<<<(NF4 + 255) / 256, blk, 0, stream>>>(H, Hxb, NF4);
    cvt_weights<<<(59392 + 255) / 256, blk, 0, stream>>>(
        gru_wih, gru_whh, lstm_wih, lstm_whh, lin_w,
        wihb, whhb, lwihb, lwhhb, linwb);
    transpose_wg_bf16<<<128, blk, 0, stream>>>(ggc_w, wgTb);

    hipMemsetAsync(cursor, 0, N_NODES * sizeof(int), stream);
    count_deg<<<EB, blk, 0, stream>>>(ei, cursor);
    scan_deg<<<1, 1024, 0, stream>>>(cursor, rowptr);
    fill_csr<<<EB, blk, 0, stream>>>(ei, ew, cursor, sSrc, sW);

    for (int layer = 0; layer < 2; ++layer) {
        mfma_gemm_m<<<MB, blk, 0, stream>>>(hb, wgTb + (size_t)layer * KD * KD, mb);
        gather_agg_bf16<<<(N_NODES * 32 + 255) / 256, blk, 0, stream>>>(
            mb, rowptr, sSrc, sW, aggb);
        gru_fused<<<MB, blk, 0, stream>>>(aggb, hb, wihb, whhb, gru_bih, gru_bhh);
    }

    lstm_fused<<<MB, blk, 0, stream>>>(hb, Hxb, C, lwihb, lwhhb,
                                       lstm_bih, lstm_bhh, h_out, c_out);
    head_gemm<<<MB, blk, 0, stream>>>(hb, linwb, lin_b, out_head);
}

// Round 5
// 427.773 us; speedup vs baseline: 9.0266x; 1.2820x over previous
//
#include <hip/hip_runtime.h>
#include <math.h>

#define N_NODES 50000
#define E_EDGES 800000
#define KD 128
#define NBLK_SCAN 196   // ceil(50000/256)

typedef __attribute__((ext_vector_type(8))) short bf16x8;
typedef __attribute__((ext_vector_type(4))) float f32x4;

__device__ __forceinline__ float sigmoidf_(float x) { return 1.f / (1.f + expf(-x)); }

__device__ __forceinline__ unsigned short f2bf(float f) {
    unsigned u = __float_as_uint(f);
    return (unsigned short)((u + 0x7FFFu + ((u >> 16) & 1u)) >> 16);
}
__device__ __forceinline__ float bf2f(unsigned short b) {
    return __uint_as_float(((unsigned)b) << 16);
}
__device__ __forceinline__ bf16x8 ldfrag(const unsigned short* p) {
    return *(const bf16x8*)(const void*)p;
}
// DMA one 1KB fragment block: lane l's 16B from per-lane gsrc -> lds + l*16
__device__ __forceinline__ void stage_frag(const unsigned short* g, unsigned short* l) {
    __builtin_amdgcn_global_load_lds(
        (const __attribute__((address_space(1))) unsigned int*)g,
        (__attribute__((address_space(3))) unsigned int*)l, 16, 0, 0);
}

// ---------------------------------------------------------------------------
// fp32 -> bf16 converts (x and H fused in one launch)
// ---------------------------------------------------------------------------
__global__ __launch_bounds__(256) void cvt_xh(const float* __restrict__ x,
                                              const float* __restrict__ H,
                                              unsigned short* __restrict__ hb,
                                              unsigned short* __restrict__ Hxb, int n4) {
    int t = blockIdx.x * 256 + threadIdx.x;
    const float* in; unsigned short* out; int idx;
    if (t < n4) { in = x; out = hb; idx = t; }
    else if (t < 2 * n4) { in = H; out = Hxb; idx = t - n4; }
    else return;
    float4 v = ((const float4*)in)[idx];
    ushort4 o;
    o.x = f2bf(v.x); o.y = f2bf(v.y); o.z = f2bf(v.z); o.w = f2bf(v.w);
    ((ushort4*)out)[idx] = o;
}

// all small weight matrices in one launch (float4 units)
__global__ __launch_bounds__(256) void cvt_weights(
        const float* __restrict__ a, const float* __restrict__ b,
        const float* __restrict__ c, const float* __restrict__ d,
        const float* __restrict__ e,
        unsigned short* __restrict__ oa, unsigned short* __restrict__ ob,
        unsigned short* __restrict__ oc, unsigned short* __restrict__ od,
        unsigned short* __restrict__ oe) {
    int t = blockIdx.x * 256 + threadIdx.x;
    const float* in; unsigned short* out; int idx;
    if      (t < 12288)  { in = a; out = oa; idx = t; }
    else if (t < 24576)  { in = b; out = ob; idx = t - 12288; }
    else if (t < 40960)  { in = c; out = oc; idx = t - 24576; }
    else if (t < 57344)  { in = d; out = od; idx = t - 40960; }
    else if (t < 59392)  { in = e; out = oe; idx = t - 57344; }
    else return;
    float4 v = ((const float4*)in)[idx];
    ushort4 o;
    o.x = f2bf(v.x); o.y = f2bf(v.y); o.z = f2bf(v.z); o.w = f2bf(v.w);
    ((ushort4*)out)[idx] = o;
}

// Transpose+convert GGC weights [2][128][128]: WT[l][c][r] = W[l][r][c]
__global__ __launch_bounds__(256) void transpose_wg_bf16(const float* __restrict__ W,
                                                         unsigned short* __restrict__ WT) {
    int t = blockIdx.x * 256 + threadIdx.x;
    int l = t >> 14;
    int r = (t >> 7) & 127;
    int c = t & 127;
    WT[l * 16384 + c * 128 + r] = f2bf(W[l * 16384 + r * 128 + c]);
}

// ---------------------------------------------------------------------------
// CSR build: degree -> 3-phase parallel exclusive scan -> fill
// ---------------------------------------------------------------------------
__global__ __launch_bounds__(256) void count_deg(const int* __restrict__ ei,
                                                 int* __restrict__ deg) {
    int e = blockIdx.x * 256 + threadIdx.x;
    if (e >= E_EDGES) return;
    atomicAdd(&deg[ei[E_EDGES + e]], 1);
}

// phase 1: intra-block exclusive scan of deg (in cursor) -> rowptr; block sums
__global__ __launch_bounds__(256) void scan_p1(const int* __restrict__ deg,
                                               int* __restrict__ excl,
                                               int* __restrict__ bsum) {
    __shared__ int part[256];
    const int t = threadIdx.x;
    const int i = blockIdx.x * 256 + t;
    int v = (i < N_NODES) ? deg[i] : 0;
    part[t] = v;
    __syncthreads();
#pragma unroll
    for (int off = 1; off < 256; off <<= 1) {
        int u = (t >= off) ? part[t - off] : 0;
        __syncthreads();
        part[t] += u;
        __syncthreads();
    }
    if (i < N_NODES) excl[i] = part[t] - v;
    if (t == 255) bsum[blockIdx.x] = part[255];
}

// phase 2: single block scans the 196 block sums in-place (exclusive); total->rowptr[N]
__global__ __launch_bounds__(256) void scan_p2(int* __restrict__ bsum,
                                               int* __restrict__ rowptrN) {
    __shared__ int part[256];
    const int t = threadIdx.x;
    int v = (t < NBLK_SCAN) ? bsum[t] : 0;
    part[t] = v;
    __syncthreads();
#pragma unroll
    for (int off = 1; off < 256; off <<= 1) {
        int u = (t >= off) ? part[t - off] : 0;
        __syncthreads();
        part[t] += u;
        __syncthreads();
    }
    if (t < NBLK_SCAN) bsum[t] = part[t] - v;
    if (t == 255) *rowptrN = part[255];
}

// phase 3: add block offsets; materialize rowptr and fill-cursor
__global__ __launch_bounds__(256) void scan_p3(const int* __restrict__ bsum,
                                               int* __restrict__ rowptr,
                                               int* __restrict__ cursor) {
    int i = blockIdx.x * 256 + threadIdx.x;
    if (i >= N_NODES) return;
    int r = rowptr[i] + bsum[blockIdx.x];
    rowptr[i] = r;
    cursor[i] = r;
}

__global__ __launch_bounds__(256) void fill_csr(const int* __restrict__ ei,
                                                const float* __restrict__ ew,
                                                int* __restrict__ cursor,
                                                int* __restrict__ sSrc,
                                                float* __restrict__ sW) {
    int e = blockIdx.x * 256 + threadIdx.x;
    if (e >= E_EDGES) return;
    int dst = ei[E_EDGES + e];
    int pos = atomicAdd(&cursor[dst], 1);
    sSrc[pos] = ei[e];
    sW[pos] = ew[e];
}

// ---------------------------------------------------------------------------
// agg[n,:] = sum_e w[e]*m[src[e],:]  (bf16, fp32 accum)
// One node per wave; halves process alternating edges; shfl_xor(32) combine.
// ---------------------------------------------------------------------------
__global__ __launch_bounds__(256) void gather_agg_bf16(const unsigned short* __restrict__ m,
                                                       const int* __restrict__ rowptr,
                                                       const int* __restrict__ sSrc,
                                                       const float* __restrict__ sW,
                                                       unsigned short* __restrict__ agg) {
    int wid = (blockIdx.x * 256 + threadIdx.x) >> 6;
    if (wid >= N_NODES) return;
    int lane = threadIdx.x & 63;
    int half = lane >> 5, li = lane & 31;
    int f0 = li << 2;
    int e0 = rowptr[wid], e1 = rowptr[wid + 1];
    float ax = 0.f, ay = 0.f, az = 0.f, aw = 0.f;
    for (int e = e0 + half; e < e1; e += 2) {
        int s = sSrc[e];
        float w = sW[e];
        ushort4 v = *(const ushort4*)(m + (size_t)s * KD + f0);
        ax += w * bf2f(v.x); ay += w * bf2f(v.y);
        az += w * bf2f(v.z); aw += w * bf2f(v.w);
    }
    ax += __shfl_xor(ax, 32, 64);
    ay += __shfl_xor(ay, 32, 64);
    az += __shfl_xor(az, 32, 64);
    aw += __shfl_xor(aw, 32, 64);
    if (half == 0) {
        ushort4 o;
        o.x = f2bf(ax); o.y = f2bf(ay); o.z = f2bf(az); o.w = f2bf(aw);
        *(ushort4*)(agg + (size_t)wid * KD + f0) = o;
    }
}

// ---------------------------------------------------------------------------
// m = h @ Wg. Weights (32 KB) staged ONCE in LDS, fragment-packed.
// ---------------------------------------------------------------------------
__global__ __launch_bounds__(256) void mfma_gemm_m(const unsigned short* __restrict__ A,
                                                   const unsigned short* __restrict__ WT,
                                                   unsigned short* __restrict__ Mout) {
    __shared__ unsigned short wlds[32 * 512];
    const int lane = threadIdx.x & 63, wave = threadIdx.x >> 6;
    const int row0 = blockIdx.x * 64 + wave * 16;
    const int rl = lane & 15, kg = lane >> 4;
    for (int f = wave; f < 32; f += 4) {
        int jt = f >> 2, kk = f & 3;
        stage_frag(WT + (size_t)(jt * 16 + rl) * KD + kk * 32 + kg * 8, wlds + f * 512);
    }
    const size_t arow = (size_t)min(row0 + rl, N_NODES - 1);
    bf16x8 a[4];
#pragma unroll
    for (int kk = 0; kk < 4; ++kk)
        a[kk] = ldfrag(A + arow * KD + kk * 32 + kg * 8);
    __syncthreads();
#pragma unroll
    for (int jt = 0; jt < 8; ++jt) {
        f32x4 acc = {0.f, 0.f, 0.f, 0.f};
#pragma unroll
        for (int kk = 0; kk < 4; ++kk)
            acc = __builtin_amdgcn_mfma_f32_16x16x32_bf16(
                a[kk], ldfrag(wlds + (jt * 4 + kk) * 512 + lane * 8), acc, 0, 0, 0);
        int col = jt * 16 + rl;
#pragma unroll
        for (int p = 0; p < 4; ++p) {
            int row = row0 + kg * 4 + p;
            if (row < N_NODES) Mout[(size_t)row * KD + col] = f2bf(acc[p]);
        }
    }
}

// ---------------------------------------------------------------------------
// Fused GRU cell, double-buffered LDS weight tiles
// ---------------------------------------------------------------------------
__global__ __launch_bounds__(256) void gru_fused(const unsigned short* __restrict__ Agg,
                                                 unsigned short* __restrict__ Hh,
                                                 const unsigned short* __restrict__ Wih,
                                                 const unsigned short* __restrict__ Whh,
                                                 const float* __restrict__ bih,
                                                 const float* __restrict__ bhh) {
    __shared__ unsigned short lds[2 * 24 * 512];
    const int lane = threadIdx.x & 63, wave = threadIdx.x >> 6;
    const int row0 = blockIdx.x * 64 + wave * 16;
    const int rl = lane & 15, kg = lane >> 4;

    auto stage = [&](int jt, int buf) {
        unsigned short* b = lds + buf * 24 * 512;
        for (int q = wave; q < 24; q += 4) {
            int s = q >> 2, kk = q & 3;
            const unsigned short* src = (s < 3 ? Wih + (size_t)s * 128 * KD
                                               : Whh + (size_t)(s - 3) * 128 * KD)
                                        + (size_t)(jt * 16 + rl) * KD + kk * 32 + kg * 8;
            stage_frag(src, b + q * 512);
        }
    };

    stage(0, 0);
    const size_t arow = (size_t)min(row0 + rl, N_NODES - 1);
    bf16x8 a1[4], a2[4];
#pragma unroll
    for (int kk = 0; kk < 4; ++kk) {
        a1[kk] = ldfrag(Agg + arow * KD + kk * 32 + kg * 8);
        a2[kk] = ldfrag(Hh + arow * KD + kk * 32 + kg * 8);
    }
    __syncthreads();

    for (int jt = 0; jt < 8; ++jt) {
        const unsigned short* cw = lds + (jt & 1) * 24 * 512;
        if (jt < 7) stage(jt + 1, (jt + 1) & 1);
        f32x4 ir = {0.f,0.f,0.f,0.f}, iz = ir, in_ = ir, hr = ir, hz = ir, hn = ir;
#pragma unroll
        for (int kk = 0; kk < 4; ++kk) {
            ir  = __builtin_amdgcn_mfma_f32_16x16x32_bf16(a1[kk], ldfrag(cw + (0*4+kk)*512 + lane*8), ir,  0, 0, 0);
            iz  = __builtin_amdgcn_mfma_f32_16x16x32_bf16(a1[kk], ldfrag(cw + (1*4+kk)*512 + lane*8), iz,  0, 0, 0);
            in_ = __builtin_amdgcn_mfma_f32_16x16x32_bf16(a1[kk], ldfrag(cw + (2*4+kk)*512 + lane*8), in_, 0, 0, 0);
            hr  = __builtin_amdgcn_mfma_f32_16x16x32_bf16(a2[kk], ldfrag(cw + (3*4+kk)*512 + lane*8), hr,  0, 0, 0);
            hz  = __builtin_amdgcn_mfma_f32_16x16x32_bf16(a2[kk], ldfrag(cw + (4*4+kk)*512 + lane*8), hz,  0, 0, 0);
            hn  = __builtin_amdgcn_mfma_f32_16x16x32_bf16(a2[kk], ldfrag(cw + (5*4+kk)*512 + lane*8), hn,  0, 0, 0);
        }
        const int col = jt * 16 + rl;
        const float b_ir = bih[col], b_iz = bih[128 + col], b_in = bih[256 + col];
        const float b_hr = bhh[col], b_hz = bhh[128 + col], b_hn = bhh[256 + col];
#pragma unroll
        for (int p = 0; p < 4; ++p) {
            int row = row0 + kg * 4 + p;
            if (row >= N_NODES) continue;
            float r = sigmoidf_(ir[p] + b_ir + hr[p] + b_hr);
            float z = sigmoidf_(iz[p] + b_iz + hz[p] + b_hz);
            float nc = tanhf(in_[p] + b_in + r * (hn[p] + b_hn));
            float hv = bf2f(Hh[(size_t)row * KD + col]);
            Hh[(size_t)row * KD + col] = f2bf((1.f - z) * nc + z * hv);
        }
        __syncthreads();
    }
}

// ---------------------------------------------------------------------------
// Fused LSTM cell, double-buffered LDS weight tiles
// ---------------------------------------------------------------------------
__global__ __launch_bounds__(256) void lstm_fused(unsigned short* __restrict__ Hh,
                                                  const unsigned short* __restrict__ Hx,
                                                  const float* __restrict__ Cx,
                                                  const unsigned short* __restrict__ Wih,
                                                  const unsigned short* __restrict__ Whh,
                                                  const float* __restrict__ bih,
                                                  const float* __restrict__ bhh,
                                                  float* __restrict__ h_out,
                                                  float* __restrict__ c_out) {
    __shared__ unsigned short lds[2 * 32 * 512];
    const int lane = threadIdx.x & 63, wave = threadIdx.x >> 6;
    const int row0 = blockIdx.x * 64 + wave * 16;
    const int rl = lane & 15, kg = lane >> 4;

    auto stage = [&](int jt, int buf) {
        unsigned short* b = lds + buf * 32 * 512;
        for (int q = wave; q < 32; q += 4) {
            int s = q >> 2, kk = q & 3;
            const unsigned short* src = (s < 4 ? Wih + (size_t)s * 128 * KD
                                               : Whh + (size_t)(s - 4) * 128 * KD)
                                        + (size_t)(jt * 16 + rl) * KD + kk * 32 + kg * 8;
            stage_frag(src, b + q * 512);
        }
    };

    stage(0, 0);
    const size_t arow = (size_t)min(row0 + rl, N_NODES - 1);
    bf16x8 a1[4], a2[4];
#pragma unroll
    for (int kk = 0; kk < 4; ++kk) {
        a1[kk] = ldfrag(Hh + arow * KD + kk * 32 + kg * 8);
        a2[kk] = ldfrag(Hx + arow * KD + kk * 32 + kg * 8);
    }
    __syncthreads();

    for (int jt = 0; jt < 8; ++jt) {
        const unsigned short* cw = lds + (jt & 1) * 32 * 512;
        if (jt < 7) stage(jt + 1, (jt + 1) & 1);
        f32x4 gi = {0.f,0.f,0.f,0.f}, gf = gi, gg = gi, go = gi;
        f32x4 hi = gi, hf = gi, hg = gi, ho = gi;
#pragma unroll
        for (int kk = 0; kk < 4; ++kk) {
            gi = __builtin_amdgcn_mfma_f32_16x16x32_bf16(a1[kk], ldfrag(cw + (0*4+kk)*512 + lane*8), gi, 0, 0, 0);
            gf = __builtin_amdgcn_mfma_f32_16x16x32_bf16(a1[kk], ldfrag(cw + (1*4+kk)*512 + lane*8), gf, 0, 0, 0);
            gg = __builtin_amdgcn_mfma_f32_16x16x32_bf16(a1[kk], ldfrag(cw + (2*4+kk)*512 + lane*8), gg, 0, 0, 0);
            go = __builtin_amdgcn_mfma_f32_16x16x32_bf16(a1[kk], ldfrag(cw + (3*4+kk)*512 + lane*8), go, 0, 0, 0);
            hi = __builtin_amdgcn_mfma_f32_16x16x32_bf16(a2[kk], ldfrag(cw + (4*4+kk)*512 + lane*8), hi, 0, 0, 0);
            hf = __builtin_amdgcn_mfma_f32_16x16x32_bf16(a2[kk], ldfrag(cw + (5*4+kk)*512 + lane*8), hf, 0, 0, 0);
            hg = __builtin_amdgcn_mfma_f32_16x16x32_bf16(a2[kk], ldfrag(cw + (6*4+kk)*512 + lane*8), hg, 0, 0, 0);
            ho = __builtin_amdgcn_mfma_f32_16x16x32_bf16(a2[kk], ldfrag(cw + (7*4+kk)*512 + lane*8), ho, 0, 0, 0);
        }
        const int col = jt * 16 + rl;
        const float b_i = bih[col] + bhh[col];
        const float b_f = bih[128 + col] + bhh[128 + col];
        const float b_g = bih[256 + col] + bhh[256 + col];
        const float b_o = bih[384 + col] + bhh[384 + col];
#pragma unroll
        for (int p = 0; p < 4; ++p) {
            int row = row0 + kg * 4 + p;
            if (row >= N_NODES) continue;
            float ig = sigmoidf_(gi[p] + hi[p] + b_i);
            float fg = sigmoidf_(gf[p] + hf[p] + b_f);
            float gv = tanhf(gg[p] + hg[p] + b_g);
            float og = sigmoidf_(go[p] + ho[p] + b_o);
            float c = fg * Cx[(size_t)row * KD + col] + ig * gv;
            float hn = og * tanhf(c);
            size_t idx = (size_t)row * KD + col;
            c_out[idx] = c;
            h_out[idx] = hn;
            Hh[idx] = f2bf(fmaxf(hn, 0.f));
        }
        __syncthreads();
    }
}

// ---------------------------------------------------------------------------
// head: out[N][64] = hrelu @ lin_wᵀ + lin_b. Weights (16 KB) staged once.
// ---------------------------------------------------------------------------
__global__ __launch_bounds__(256) void head_gemm(const unsigned short* __restrict__ Hr,
                                                 const unsigned short* __restrict__ LinW,
                                                 const float* __restrict__ lin_b,
                                                 float* __restrict__ Out) {
    __shared__ unsigned short wlds[16 * 512];
    const int lane = threadIdx.x & 63, wave = threadIdx.x >> 6;
    const int row0 = blockIdx.x * 64 + wave * 16;
    const int rl = lane & 15, kg = lane >> 4;
    for (int f = wave; f < 16; f += 4) {
        int jt = f >> 2, kk = f & 3;
        stage_frag(LinW + (size_t)(jt * 16 + rl) * KD + kk * 32 + kg * 8, wlds + f * 512);
    }
    const size_t arow = (size_t)min(row0 + rl, N_NODES - 1);
    bf16x8 a[4];
#pragma unroll
    for (int kk = 0; kk < 4; ++kk)
        a[kk] = ldfrag(Hr + arow * KD + kk * 32 + kg * 8);
    __syncthreads();
#pragma unroll
    for (int jt = 0; jt < 4; ++jt) {
        f32x4 acc = {0.f, 0.f, 0.f, 0.f};
#pragma unroll
        for (int kk = 0; kk < 4; ++kk)
            acc = __builtin_amdgcn_mfma_f32_16x16x32_bf16(
                a[kk], ldfrag(wlds + (jt * 4 + kk) * 512 + lane * 8), acc, 0, 0, 0);
        int col = jt * 16 + rl;
        float b = lin_b[col];
#pragma unroll
        for (int p = 0; p < 4; ++p) {
            int row = row0 + kg * 4 + p;
            if (row < N_NODES) Out[(size_t)row * 64 + col] = acc[p] + b;
        }
    }
}

extern "C" void kernel_launch(void* const* d_in, const int* in_sizes, int n_in,
                              void* d_out, int out_size, void* d_ws, size_t ws_size,
                              hipStream_t stream) {
    const float* x        = (const float*)d_in[0];
    const int*   ei       = (const int*)d_in[1];
    const float* ew       = (const float*)d_in[2];
    const float* H        = (const float*)d_in[3];
    const float* C        = (const float*)d_in[4];
    const float* ggc_w    = (const float*)d_in[5];
    const float* gru_wih  = (const float*)d_in[6];
    const float* gru_whh  = (const float*)d_in[7];
    const float* gru_bih  = (const float*)d_in[8];
    const float* gru_bhh  = (const float*)d_in[9];
    const float* lstm_wih = (const float*)d_in[10];
    const float* lstm_whh = (const float*)d_in[11];
    const float* lstm_bih = (const float*)d_in[12];
    const float* lstm_bhh = (const float*)d_in[13];
    const float* lin_w    = (const float*)d_in[14];
    const float* lin_b    = (const float*)d_in[15];

    float* out_head = (float*)d_out;                   // [N][64]
    float* h_out = out_head + (size_t)N_NODES * 64;    // h_new [N][128]
    float* c_out = h_out + (size_t)N_NODES * KD;       // c_new [N][128]

    char* w = (char*)d_ws;
    unsigned short* hb    = (unsigned short*)w; w += (size_t)N_NODES * KD * 2;
    unsigned short* Hxb   = (unsigned short*)w; w += (size_t)N_NODES * KD * 2;
    unsigned short* mb    = (unsigned short*)w; w += (size_t)N_NODES * KD * 2;
    unsigned short* aggb  = (unsigned short*)w; w += (size_t)N_NODES * KD * 2;
    unsigned short* wgTb  = (unsigned short*)w; w += 2 * KD * KD * 2;
    unsigned short* wihb  = (unsigned short*)w; w += 384 * KD * 2;
    unsigned short* whhb  = (unsigned short*)w; w += 384 * KD * 2;
    unsigned short* lwihb = (unsigned short*)w; w += 512 * KD * 2;
    unsigned short* lwhhb = (unsigned short*)w; w += 512 * KD * 2;
    unsigned short* linwb = (unsigned short*)w; w += 64 * KD * 2;
    int*   rowptr = (int*)w; w += 50304 * 4;
    int*   cursor = (int*)w; w += 50304 * 4;
    int*   bsum   = (int*)w; w += 256 * 4;
    int*   sSrc   = (int*)w; w += (size_t)E_EDGES * 4;
    float* sW     = (float*)w; w += (size_t)E_EDGES * 4;

    dim3 blk(256);
    const int MB = (N_NODES + 63) / 64;
    const int EB = (E_EDGES + 255) / 256;
    const int NF4 = N_NODES * KD / 4;

    cvt_xh<<<(2 * NF4 + 255) / 256, blk, 0, stream>>>(x, H, hb, Hxb, NF4);
    cvt_weights<<<(59392 + 255) / 256, blk, 0, stream>>>(
        gru_wih, gru_whh, lstm_wih, lstm_whh, lin_w,
        wihb, whhb, lwihb, lwhhb, linwb);
    transpose_wg_bf16<<<128, blk, 0, stream>>>(ggc_w, wgTb);

    // CSR build with 3-phase parallel scan
    hipMemsetAsync(cursor, 0, N_NODES * sizeof(int), stream);
    count_deg<<<EB, blk, 0, stream>>>(ei, cursor);
    scan_p1<<<NBLK_SCAN, blk, 0, stream>>>(cursor, rowptr, bsum);
    scan_p2<<<1, blk, 0, stream>>>(bsum, rowptr + N_NODES);
    scan_p3<<<NBLK_SCAN, blk, 0, stream>>>(bsum, rowptr, cursor);
    fill_csr<<<EB, blk, 0, stream>>>(ei, ew, cursor, sSrc, sW);

    for (int layer = 0; layer < 2; ++layer) {
        mfma_gemm_m<<<MB, blk, 0, stream>>>(hb, wgTb + (size_t)layer * KD * KD, mb);
        gather_agg_bf16<<<(N_NODES * 64 + 255) / 256, blk, 0, stream>>>(
            mb, rowptr, sSrc, sW, aggb);
        gru_fused<<<MB, blk, 0, stream>>>(aggb, hb, wihb, whhb, gru_bih, gru_bhh);
    }

    lstm_fused<<<MB, blk, 0, stream>>>(hb, Hxb, C, lwihb, lwhhb,
                                       lstm_bih, lstm_bhh, h_out, c_out);
    head_gemm<<<MB, blk, 0, stream>>>(hb, linwb, lin_b, out_head);
}

// Round 6
// 379.873 us; speedup vs baseline: 10.1648x; 1.1261x over previous
//
#include <hip/hip_runtime.h>
#include <math.h>

#define N_NODES 50000
#define E_EDGES 800000
#define KD 128
#define NBLK_SCAN 196   // ceil(50000/256)
#define RT_TILES 3125   // N_NODES / 16 (exact)

typedef __attribute__((ext_vector_type(8))) short bf16x8;
typedef __attribute__((ext_vector_type(4))) float f32x4;

__device__ __forceinline__ float fsig(float x) { return 1.f / (1.f + __expf(-x)); }
// NaN-free tanh: x->+inf => 1, x->-inf => -1
__device__ __forceinline__ float ftanh(float x) { return 1.f - 2.f / (1.f + __expf(2.f * x)); }

__device__ __forceinline__ unsigned short f2bf(float f) {
    unsigned u = __float_as_uint(f);
    return (unsigned short)((u + 0x7FFFu + ((u >> 16) & 1u)) >> 16);
}
__device__ __forceinline__ float bf2f(unsigned short b) {
    return __uint_as_float(((unsigned)b) << 16);
}
__device__ __forceinline__ bf16x8 ldfrag(const unsigned short* p) {
    return *(const bf16x8*)(const void*)p;
}
// DMA one 1KB fragment block: lane l's 16B from per-lane gsrc -> lds + l*16
__device__ __forceinline__ void stage_frag(const unsigned short* g, unsigned short* l) {
    __builtin_amdgcn_global_load_lds(
        (const __attribute__((address_space(1))) unsigned int*)g,
        (__attribute__((address_space(3))) unsigned int*)l, 16, 0, 0);
}

// ---------------------------------------------------------------------------
// fp32 -> bf16 converts
// ---------------------------------------------------------------------------
__global__ __launch_bounds__(256) void cvt_xh(const float* __restrict__ x,
                                              const float* __restrict__ H,
                                              unsigned short* __restrict__ hb,
                                              unsigned short* __restrict__ Hxb, int n4) {
    int t = blockIdx.x * 256 + threadIdx.x;
    const float* in; unsigned short* out; int idx;
    if (t < n4) { in = x; out = hb; idx = t; }
    else if (t < 2 * n4) { in = H; out = Hxb; idx = t - n4; }
    else return;
    float4 v = ((const float4*)in)[idx];
    ushort4 o;
    o.x = f2bf(v.x); o.y = f2bf(v.y); o.z = f2bf(v.z); o.w = f2bf(v.w);
    ((ushort4*)out)[idx] = o;
}

__global__ __launch_bounds__(256) void cvt_weights(
        const float* __restrict__ a, const float* __restrict__ b,
        const float* __restrict__ c, const float* __restrict__ d,
        const float* __restrict__ e,
        unsigned short* __restrict__ oa, unsigned short* __restrict__ ob,
        unsigned short* __restrict__ oc, unsigned short* __restrict__ od,
        unsigned short* __restrict__ oe) {
    int t = blockIdx.x * 256 + threadIdx.x;
    const float* in; unsigned short* out; int idx;
    if      (t < 12288)  { in = a; out = oa; idx = t; }
    else if (t < 24576)  { in = b; out = ob; idx = t - 12288; }
    else if (t < 40960)  { in = c; out = oc; idx = t - 24576; }
    else if (t < 57344)  { in = d; out = od; idx = t - 40960; }
    else if (t < 59392)  { in = e; out = oe; idx = t - 57344; }
    else return;
    float4 v = ((const float4*)in)[idx];
    ushort4 o;
    o.x = f2bf(v.x); o.y = f2bf(v.y); o.z = f2bf(v.z); o.w = f2bf(v.w);
    ((ushort4*)out)[idx] = o;
}

__global__ __launch_bounds__(256) void transpose_wg_bf16(const float* __restrict__ W,
                                                         unsigned short* __restrict__ WT) {
    int t = blockIdx.x * 256 + threadIdx.x;
    int l = t >> 14;
    int r = (t >> 7) & 127;
    int c = t & 127;
    WT[l * 16384 + c * 128 + r] = f2bf(W[l * 16384 + r * 128 + c]);
}

// ---------------------------------------------------------------------------
// CSR build
// ---------------------------------------------------------------------------
__global__ __launch_bounds__(256) void count_deg(const int* __restrict__ ei,
                                                 int* __restrict__ deg) {
    int e = blockIdx.x * 256 + threadIdx.x;
    if (e >= E_EDGES) return;
    atomicAdd(&deg[ei[E_EDGES + e]], 1);
}

__global__ __launch_bounds__(256) void scan_p1(const int* __restrict__ deg,
                                               int* __restrict__ excl,
                                               int* __restrict__ bsum) {
    __shared__ int part[256];
    const int t = threadIdx.x;
    const int i = blockIdx.x * 256 + t;
    int v = (i < N_NODES) ? deg[i] : 0;
    part[t] = v;
    __syncthreads();
#pragma unroll
    for (int off = 1; off < 256; off <<= 1) {
        int u = (t >= off) ? part[t - off] : 0;
        __syncthreads();
        part[t] += u;
        __syncthreads();
    }
    if (i < N_NODES) excl[i] = part[t] - v;
    if (t == 255) bsum[blockIdx.x] = part[255];
}

__global__ __launch_bounds__(256) void scan_p2(int* __restrict__ bsum,
                                               int* __restrict__ rowptrN) {
    __shared__ int part[256];
    const int t = threadIdx.x;
    int v = (t < NBLK_SCAN) ? bsum[t] : 0;
    part[t] = v;
    __syncthreads();
#pragma unroll
    for (int off = 1; off < 256; off <<= 1) {
        int u = (t >= off) ? part[t - off] : 0;
        __syncthreads();
        part[t] += u;
        __syncthreads();
    }
    if (t < NBLK_SCAN) bsum[t] = part[t] - v;
    if (t == 255) *rowptrN = part[255];
}

__global__ __launch_bounds__(256) void scan_p3(const int* __restrict__ bsum,
                                               int* __restrict__ rowptr,
                                               int* __restrict__ cursor) {
    int i = blockIdx.x * 256 + threadIdx.x;
    if (i >= N_NODES) return;
    int r = rowptr[i] + bsum[blockIdx.x];
    rowptr[i] = r;
    cursor[i] = r;
}

__global__ __launch_bounds__(256) void fill_csr(const int* __restrict__ ei,
                                                const float* __restrict__ ew,
                                                int* __restrict__ cursor,
                                                int* __restrict__ sSrc,
                                                float* __restrict__ sW) {
    int e = blockIdx.x * 256 + threadIdx.x;
    if (e >= E_EDGES) return;
    int dst = ei[E_EDGES + e];
    int pos = atomicAdd(&cursor[dst], 1);
    sSrc[pos] = ei[e];
    sW[pos] = ew[e];
}

// ---------------------------------------------------------------------------
// agg[n,:] = sum_e w[e]*m[src[e],:]  (bf16, fp32 accum); one node per wave
// ---------------------------------------------------------------------------
__global__ __launch_bounds__(256) void gather_agg_bf16(const unsigned short* __restrict__ m,
                                                       const int* __restrict__ rowptr,
                                                       const int* __restrict__ sSrc,
                                                       const float* __restrict__ sW,
                                                       unsigned short* __restrict__ agg) {
    int wid = (blockIdx.x * 256 + threadIdx.x) >> 6;
    if (wid >= N_NODES) return;
    int lane = threadIdx.x & 63;
    int half = lane >> 5, li = lane & 31;
    int f0 = li << 2;
    int e0 = rowptr[wid], e1 = rowptr[wid + 1];
    float ax = 0.f, ay = 0.f, az = 0.f, aw = 0.f;
    for (int e = e0 + half; e < e1; e += 2) {
        int s = sSrc[e];
        float w = sW[e];
        ushort4 v = *(const ushort4*)(m + (size_t)s * KD + f0);
        ax += w * bf2f(v.x); ay += w * bf2f(v.y);
        az += w * bf2f(v.z); aw += w * bf2f(v.w);
    }
    ax += __shfl_xor(ax, 32, 64);
    ay += __shfl_xor(ay, 32, 64);
    az += __shfl_xor(az, 32, 64);
    aw += __shfl_xor(aw, 32, 64);
    if (half == 0) {
        ushort4 o;
        o.x = f2bf(ax); o.y = f2bf(ay); o.z = f2bf(az); o.w = f2bf(aw);
        *(ushort4*)(agg + (size_t)wid * KD + f0) = o;
    }
}

// ---------------------------------------------------------------------------
// m = h @ Wg. 32 KB weights staged once; waves grid-stride over row tiles.
// ---------------------------------------------------------------------------
__global__ __launch_bounds__(256) void mfma_gemm_m(const unsigned short* __restrict__ A,
                                                   const unsigned short* __restrict__ WT,
                                                   unsigned short* __restrict__ Mout) {
    __shared__ unsigned short wlds[32 * 512];
    const int lane = threadIdx.x & 63, wave = threadIdx.x >> 6;
    const int rl = lane & 15, kg = lane >> 4;
    for (int f = wave; f < 32; f += 4) {
        int jt = f >> 2, kk = f & 3;
        stage_frag(WT + (size_t)(jt * 16 + rl) * KD + kk * 32 + kg * 8, wlds + f * 512);
    }
    __syncthreads();
    const int stride = gridDim.x << 2;
    for (int rt = blockIdx.x * 4 + wave; rt < RT_TILES; rt += stride) {
        const size_t arow = (size_t)rt * 16 + rl;
        bf16x8 a[4];
#pragma unroll
        for (int kk = 0; kk < 4; ++kk)
            a[kk] = ldfrag(A + arow * KD + kk * 32 + kg * 8);
#pragma unroll
        for (int jt = 0; jt < 8; ++jt) {
            f32x4 acc = {0.f, 0.f, 0.f, 0.f};
#pragma unroll
            for (int kk = 0; kk < 4; ++kk)
                acc = __builtin_amdgcn_mfma_f32_16x16x32_bf16(
                    a[kk], ldfrag(wlds + (jt * 4 + kk) * 512 + lane * 8), acc, 0, 0, 0);
            int col = jt * 16 + rl;
#pragma unroll
            for (int p = 0; p < 4; ++p)
                Mout[(size_t)(rt * 16 + kg * 4 + p) * KD + col] = f2bf(acc[p]);
        }
    }
}

// ---------------------------------------------------------------------------
// Column-split fused GRU: block owns gate-cols [col0, col0+16); stages its
// 24 KB weight slice once; waves grid-stride over row tiles; NO inner barriers.
// Ping-pong: reads Hin, writes Hout.
// ---------------------------------------------------------------------------
__global__ __launch_bounds__(256) void gru_fused(const unsigned short* __restrict__ Agg,
                                                 const unsigned short* __restrict__ Hin,
                                                 unsigned short* __restrict__ Hout,
                                                 const unsigned short* __restrict__ Wih,
                                                 const unsigned short* __restrict__ Whh,
                                                 const float* __restrict__ bih,
                                                 const float* __restrict__ bhh) {
    __shared__ unsigned short lds[24 * 512];   // 24 KB
    const int lane = threadIdx.x & 63, wave = threadIdx.x >> 6;
    const int rl = lane & 15, kg = lane >> 4;
    const int col0 = blockIdx.y * 16;
    for (int q = wave; q < 24; q += 4) {
        int s = q >> 2, kk = q & 3;
        const unsigned short* src = (s < 3 ? Wih + (size_t)s * 128 * KD
                                           : Whh + (size_t)(s - 3) * 128 * KD)
                                    + (size_t)(col0 + rl) * KD + kk * 32 + kg * 8;
        stage_frag(src, lds + q * 512);
    }
    __syncthreads();
    const int col = col0 + rl;
    const float b_ir = bih[col], b_iz = bih[128 + col], b_in = bih[256 + col];
    const float b_hr = bhh[col], b_hz = bhh[128 + col], b_hn = bhh[256 + col];
    const int stride = gridDim.x << 2;
    for (int rt = blockIdx.x * 4 + wave; rt < RT_TILES; rt += stride) {
        const size_t arow = (size_t)rt * 16 + rl;
        bf16x8 a1[4], a2[4];
#pragma unroll
        for (int kk = 0; kk < 4; ++kk) {
            a1[kk] = ldfrag(Agg + arow * KD + kk * 32 + kg * 8);
            a2[kk] = ldfrag(Hin + arow * KD + kk * 32 + kg * 8);
        }
        f32x4 ir = {0.f,0.f,0.f,0.f}, iz = ir, in_ = ir, hr = ir, hz = ir, hn = ir;
#pragma unroll
        for (int kk = 0; kk < 4; ++kk) {
            ir  = __builtin_amdgcn_mfma_f32_16x16x32_bf16(a1[kk], ldfrag(lds + (0*4+kk)*512 + lane*8), ir,  0, 0, 0);
            iz  = __builtin_amdgcn_mfma_f32_16x16x32_bf16(a1[kk], ldfrag(lds + (1*4+kk)*512 + lane*8), iz,  0, 0, 0);
            in_ = __builtin_amdgcn_mfma_f32_16x16x32_bf16(a1[kk], ldfrag(lds + (2*4+kk)*512 + lane*8), in_, 0, 0, 0);
            hr  = __builtin_amdgcn_mfma_f32_16x16x32_bf16(a2[kk], ldfrag(lds + (3*4+kk)*512 + lane*8), hr,  0, 0, 0);
            hz  = __builtin_amdgcn_mfma_f32_16x16x32_bf16(a2[kk], ldfrag(lds + (4*4+kk)*512 + lane*8), hz,  0, 0, 0);
            hn  = __builtin_amdgcn_mfma_f32_16x16x32_bf16(a2[kk], ldfrag(lds + (5*4+kk)*512 + lane*8), hn,  0, 0, 0);
        }
#pragma unroll
        for (int p = 0; p < 4; ++p) {
            int row = rt * 16 + kg * 4 + p;
            float r = fsig(ir[p] + b_ir + hr[p] + b_hr);
            float z = fsig(iz[p] + b_iz + hz[p] + b_hz);
            float nc = ftanh(in_[p] + b_in + r * (hn[p] + b_hn));
            float hv = bf2f(Hin[(size_t)row * KD + col]);
            Hout[(size_t)row * KD + col] = f2bf((1.f - z) * nc + z * hv);
        }
    }
}

// ---------------------------------------------------------------------------
// Column-split fused LSTM: 32 KB weight slice staged once; no inner barriers.
// Writes h_new/c_new fp32 and relu(h_new) bf16 (separate buffer for head).
// ---------------------------------------------------------------------------
__global__ __launch_bounds__(256) void lstm_fused(const unsigned short* __restrict__ Hh,
                                                  const unsigned short* __restrict__ Hx,
                                                  const float* __restrict__ Cx,
                                                  const unsigned short* __restrict__ Wih,
                                                  const unsigned short* __restrict__ Whh,
                                                  const float* __restrict__ bih,
                                                  const float* __restrict__ bhh,
                                                  float* __restrict__ h_out,
                                                  float* __restrict__ c_out,
                                                  unsigned short* __restrict__ Hrelu) {
    __shared__ unsigned short lds[32 * 512];   // 32 KB
    const int lane = threadIdx.x & 63, wave = threadIdx.x >> 6;
    const int rl = lane & 15, kg = lane >> 4;
    const int col0 = blockIdx.y * 16;
    for (int q = wave; q < 32; q += 4) {
        int s = q >> 2, kk = q & 3;
        const unsigned short* src = (s < 4 ? Wih + (size_t)s * 128 * KD
                                           : Whh + (size_t)(s - 4) * 128 * KD)
                                    + (size_t)(col0 + rl) * KD + kk * 32 + kg * 8;
        stage_frag(src, lds + q * 512);
    }
    __syncthreads();
    const int col = col0 + rl;
    const float b_i = bih[col] + bhh[col];
    const float b_f = bih[128 + col] + bhh[128 + col];
    const float b_g = bih[256 + col] + bhh[256 + col];
    const float b_o = bih[384 + col] + bhh[384 + col];
    const int stride = gridDim.x << 2;
    for (int rt = blockIdx.x * 4 + wave; rt < RT_TILES; rt += stride) {
        const size_t arow = (size_t)rt * 16 + rl;
        bf16x8 a1[4], a2[4];
#pragma unroll
        for (int kk = 0; kk < 4; ++kk) {
            a1[kk] = ldfrag(Hh + arow * KD + kk * 32 + kg * 8);
            a2[kk] = ldfrag(Hx + arow * KD + kk * 32 + kg * 8);
        }
        f32x4 gi = {0.f,0.f,0.f,0.f}, gf = gi, gg = gi, go = gi;
        f32x4 hi = gi, hf = gi, hg = gi, ho = gi;
#pragma unroll
        for (int kk = 0; kk < 4; ++kk) {
            gi = __builtin_amdgcn_mfma_f32_16x16x32_bf16(a1[kk], ldfrag(lds + (0*4+kk)*512 + lane*8), gi, 0, 0, 0);
            gf = __builtin_amdgcn_mfma_f32_16x16x32_bf16(a1[kk], ldfrag(lds + (1*4+kk)*512 + lane*8), gf, 0, 0, 0);
            gg = __builtin_amdgcn_mfma_f32_16x16x32_bf16(a1[kk], ldfrag(lds + (2*4+kk)*512 + lane*8), gg, 0, 0, 0);
            go = __builtin_amdgcn_mfma_f32_16x16x32_bf16(a1[kk], ldfrag(lds + (3*4+kk)*512 + lane*8), go, 0, 0, 0);
            hi = __builtin_amdgcn_mfma_f32_16x16x32_bf16(a2[kk], ldfrag(lds + (4*4+kk)*512 + lane*8), hi, 0, 0, 0);
            hf = __builtin_amdgcn_mfma_f32_16x16x32_bf16(a2[kk], ldfrag(lds + (5*4+kk)*512 + lane*8), hf, 0, 0, 0);
            hg = __builtin_amdgcn_mfma_f32_16x16x32_bf16(a2[kk], ldfrag(lds + (6*4+kk)*512 + lane*8), hg, 0, 0, 0);
            ho = __builtin_amdgcn_mfma_f32_16x16x32_bf16(a2[kk], ldfrag(lds + (7*4+kk)*512 + lane*8), ho, 0, 0, 0);
        }
#pragma unroll
        for (int p = 0; p < 4; ++p) {
            int row = rt * 16 + kg * 4 + p;
            size_t idx = (size_t)row * KD + col;
            float ig = fsig(gi[p] + hi[p] + b_i);
            float fg = fsig(gf[p] + hf[p] + b_f);
            float gv = ftanh(gg[p] + hg[p] + b_g);
            float og = fsig(go[p] + ho[p] + b_o);
            float c = fg * Cx[idx] + ig * gv;
            float hn = og * ftanh(c);
            c_out[idx] = c;
            h_out[idx] = hn;
            Hrelu[idx] = f2bf(fmaxf(hn, 0.f));
        }
    }
}

// ---------------------------------------------------------------------------
// head: out[N][64] = hrelu @ lin_wᵀ + lin_b. 16 KB staged once; row-stride.
// ---------------------------------------------------------------------------
__global__ __launch_bounds__(256) void head_gemm(const unsigned short* __restrict__ Hr,
                                                 const unsigned short* __restrict__ LinW,
                                                 const float* __restrict__ lin_b,
                                                 float* __restrict__ Out) {
    __shared__ unsigned short wlds[16 * 512];
    const int lane = threadIdx.x & 63, wave = threadIdx.x >> 6;
    const int rl = lane & 15, kg = lane >> 4;
    for (int f = wave; f < 16; f += 4) {
        int jt = f >> 2, kk = f & 3;
        stage_frag(LinW + (size_t)(jt * 16 + rl) * KD + kk * 32 + kg * 8, wlds + f * 512);
    }
    __syncthreads();
    const int stride = gridDim.x << 2;
    for (int rt = blockIdx.x * 4 + wave; rt < RT_TILES; rt += stride) {
        const size_t arow = (size_t)rt * 16 + rl;
        bf16x8 a[4];
#pragma unroll
        for (int kk = 0; kk < 4; ++kk)
            a[kk] = ldfrag(Hr + arow * KD + kk * 32 + kg * 8);
#pragma unroll
        for (int jt = 0; jt < 4; ++jt) {
            f32x4 acc = {0.f, 0.f, 0.f, 0.f};
#pragma unroll
            for (int kk = 0; kk < 4; ++kk)
                acc = __builtin_amdgcn_mfma_f32_16x16x32_bf16(
                    a[kk], ldfrag(wlds + (jt * 4 + kk) * 512 + lane * 8), acc, 0, 0, 0);
            int col = jt * 16 + rl;
            float b = lin_b[col];
#pragma unroll
            for (int p = 0; p < 4; ++p)
                Out[(size_t)(rt * 16 + kg * 4 + p) * 64 + col] = acc[p] + b;
        }
    }
}

extern "C" void kernel_launch(void* const* d_in, const int* in_sizes, int n_in,
                              void* d_out, int out_size, void* d_ws, size_t ws_size,
                              hipStream_t stream) {
    const float* x        = (const float*)d_in[0];
    const int*   ei       = (const int*)d_in[1];
    const float* ew       = (const float*)d_in[2];
    const float* H        = (const float*)d_in[3];
    const float* C        = (const float*)d_in[4];
    const float* ggc_w    = (const float*)d_in[5];
    const float* gru_wih  = (const float*)d_in[6];
    const float* gru_whh  = (const float*)d_in[7];
    const float* gru_bih  = (const float*)d_in[8];
    const float* gru_bhh  = (const float*)d_in[9];
    const float* lstm_wih = (const float*)d_in[10];
    const float* lstm_whh = (const float*)d_in[11];
    const float* lstm_bih = (const float*)d_in[12];
    const float* lstm_bhh = (const float*)d_in[13];
    const float* lin_w    = (const float*)d_in[14];
    const float* lin_b    = (const float*)d_in[15];

    float* out_head = (float*)d_out;                   // [N][64]
    float* h_out = out_head + (size_t)N_NODES * 64;    // h_new [N][128]
    float* c_out = h_out + (size_t)N_NODES * KD;       // c_new [N][128]

    char* w = (char*)d_ws;
    unsigned short* hb    = (unsigned short*)w; w += (size_t)N_NODES * KD * 2;  // h (even layers)
    unsigned short* hb1   = (unsigned short*)w; w += (size_t)N_NODES * KD * 2;  // h (odd layers)
    unsigned short* Hxb   = (unsigned short*)w; w += (size_t)N_NODES * KD * 2;
    unsigned short* mb    = (unsigned short*)w; w += (size_t)N_NODES * KD * 2;  // m, then hrelu
    unsigned short* aggb  = (unsigned short*)w; w += (size_t)N_NODES * KD * 2;
    unsigned short* wgTb  = (unsigned short*)w; w += 2 * KD * KD * 2;
    unsigned short* wihb  = (unsigned short*)w; w += 384 * KD * 2;
    unsigned short* whhb  = (unsigned short*)w; w += 384 * KD * 2;
    unsigned short* lwihb = (unsigned short*)w; w += 512 * KD * 2;
    unsigned short* lwhhb = (unsigned short*)w; w += 512 * KD * 2;
    unsigned short* linwb = (unsigned short*)w; w += 64 * KD * 2;
    int*   rowptr = (int*)w; w += 50304 * 4;
    int*   cursor = (int*)w; w += 50304 * 4;
    int*   bsum   = (int*)w; w += 256 * 4;
    int*   sSrc   = (int*)w; w += (size_t)E_EDGES * 4;
    float* sW     = (float*)w; w += (size_t)E_EDGES * 4;

    dim3 blk(256);
    const int EB = (E_EDGES + 255) / 256;
    const int NF4 = N_NODES * KD / 4;
    const dim3 cellGrid(98, 8);   // 784 blocks; waves grid-stride rows

    cvt_xh<<<(2 * NF4 + 255) / 256, blk, 0, stream>>>(x, H, hb, Hxb, NF4);
    cvt_weights<<<(59392 + 255) / 256, blk, 0, stream>>>(
        gru_wih, gru_whh, lstm_wih, lstm_whh, lin_w,
        wihb, whhb, lwihb, lwhhb, linwb);
    transpose_wg_bf16<<<128, blk, 0, stream>>>(ggc_w, wgTb);

    // CSR build with 3-phase parallel scan
    hipMemsetAsync(cursor, 0, N_NODES * sizeof(int), stream);
    count_deg<<<EB, blk, 0, stream>>>(ei, cursor);
    scan_p1<<<NBLK_SCAN, blk, 0, stream>>>(cursor, rowptr, bsum);
    scan_p2<<<1, blk, 0, stream>>>(bsum, rowptr + N_NODES);
    scan_p3<<<NBLK_SCAN, blk, 0, stream>>>(bsum, rowptr, cursor);
    fill_csr<<<EB, blk, 0, stream>>>(ei, ew, cursor, sSrc, sW);

    // layer 0: h = hb -> hb1 ; layer 1: h = hb1 -> hb
    mfma_gemm_m<<<391, blk, 0, stream>>>(hb, wgTb, mb);
    gather_agg_bf16<<<(N_NODES * 64 + 255) / 256, blk, 0, stream>>>(
        mb, rowptr, sSrc, sW, aggb);
    gru_fused<<<cellGrid, blk, 0, stream>>>(aggb, hb, hb1, wihb, whhb, gru_bih, gru_bhh);

    mfma_gemm_m<<<391, blk, 0, stream>>>(hb1, wgTb + (size_t)KD * KD, mb);
    gather_agg_bf16<<<(N_NODES * 64 + 255) / 256, blk, 0, stream>>>(
        mb, rowptr, sSrc, sW, aggb);
    gru_fused<<<cellGrid, blk, 0, stream>>>(aggb, hb1, hb, wihb, whhb, gru_bih, gru_bhh);

    lstm_fused<<<cellGrid, blk, 0, stream>>>(hb, Hxb, C, lwihb, lwhhb,
                                             lstm_bih, lstm_bhh, h_out, c_out, mb);
    head_gemm<<<391, blk, 0, stream>>>(mb, linwb, lin_b, out_head);
}

// Round 7
// 366.482 us; speedup vs baseline: 10.5362x; 1.0365x over previous
//
#include <hip/hip_runtime.h>
#include <math.h>

#define N_NODES 50000
#define E_EDGES 800000
#define KD 128
#define NBLK_SCAN 196   // ceil(50000/256)
#define RT_TILES 3125   // N_NODES / 16 (exact)

typedef __attribute__((ext_vector_type(8))) short bf16x8;
typedef __attribute__((ext_vector_type(4))) float f32x4;

__device__ __forceinline__ float fsig(float x) { return 1.f / (1.f + __expf(-x)); }
__device__ __forceinline__ float ftanh(float x) { return 1.f - 2.f / (1.f + __expf(2.f * x)); }

__device__ __forceinline__ unsigned short f2bf(float f) {
    unsigned u = __float_as_uint(f);
    return (unsigned short)((u + 0x7FFFu + ((u >> 16) & 1u)) >> 16);
}
__device__ __forceinline__ float bf2f(unsigned short b) {
    return __uint_as_float(((unsigned)b) << 16);
}
__device__ __forceinline__ bf16x8 ldfrag(const unsigned short* p) {
    return *(const bf16x8*)(const void*)p;
}
__device__ __forceinline__ void stage_frag(const unsigned short* g, unsigned short* l) {
    __builtin_amdgcn_global_load_lds(
        (const __attribute__((address_space(1))) unsigned int*)g,
        (__attribute__((address_space(3))) unsigned int*)l, 16, 0, 0);
}

// ---------------------------------------------------------------------------
// fp32 -> bf16 converts
// ---------------------------------------------------------------------------
__global__ __launch_bounds__(256) void cvt_xh(const float* __restrict__ x,
                                              const float* __restrict__ H,
                                              unsigned short* __restrict__ hb,
                                              unsigned short* __restrict__ Hxb, int n4) {
    int t = blockIdx.x * 256 + threadIdx.x;
    const float* in; unsigned short* out; int idx;
    if (t < n4) { in = x; out = hb; idx = t; }
    else if (t < 2 * n4) { in = H; out = Hxb; idx = t - n4; }
    else return;
    float4 v = ((const float4*)in)[idx];
    ushort4 o;
    o.x = f2bf(v.x); o.y = f2bf(v.y); o.z = f2bf(v.z); o.w = f2bf(v.w);
    ((ushort4*)out)[idx] = o;
}

__global__ __launch_bounds__(256) void cvt_weights(
        const float* __restrict__ a, const float* __restrict__ b,
        const float* __restrict__ c, const float* __restrict__ d,
        const float* __restrict__ e,
        unsigned short* __restrict__ oa, unsigned short* __restrict__ ob,
        unsigned short* __restrict__ oc, unsigned short* __restrict__ od,
        unsigned short* __restrict__ oe) {
    int t = blockIdx.x * 256 + threadIdx.x;
    const float* in; unsigned short* out; int idx;
    if      (t < 12288)  { in = a; out = oa; idx = t; }
    else if (t < 24576)  { in = b; out = ob; idx = t - 12288; }
    else if (t < 40960)  { in = c; out = oc; idx = t - 24576; }
    else if (t < 57344)  { in = d; out = od; idx = t - 40960; }
    else if (t < 59392)  { in = e; out = oe; idx = t - 57344; }
    else return;
    float4 v = ((const float4*)in)[idx];
    ushort4 o;
    o.x = f2bf(v.x); o.y = f2bf(v.y); o.z = f2bf(v.z); o.w = f2bf(v.w);
    ((ushort4*)out)[idx] = o;
}

__global__ __launch_bounds__(256) void transpose_wg_bf16(const float* __restrict__ W,
                                                         unsigned short* __restrict__ WT) {
    int t = blockIdx.x * 256 + threadIdx.x;
    int l = t >> 14;
    int r = (t >> 7) & 127;
    int c = t & 127;
    WT[l * 16384 + c * 128 + r] = f2bf(W[l * 16384 + r * 128 + c]);
}

// ---------------------------------------------------------------------------
// CSR build
// ---------------------------------------------------------------------------
__global__ __launch_bounds__(256) void count_deg(const int* __restrict__ ei,
                                                 int* __restrict__ deg) {
    int e = blockIdx.x * 256 + threadIdx.x;
    if (e >= E_EDGES) return;
    atomicAdd(&deg[ei[E_EDGES + e]], 1);
}

__global__ __launch_bounds__(256) void scan_p1(const int* __restrict__ deg,
                                               int* __restrict__ excl,
                                               int* __restrict__ bsum) {
    __shared__ int part[256];
    const int t = threadIdx.x;
    const int i = blockIdx.x * 256 + t;
    int v = (i < N_NODES) ? deg[i] : 0;
    part[t] = v;
    __syncthreads();
#pragma unroll
    for (int off = 1; off < 256; off <<= 1) {
        int u = (t >= off) ? part[t - off] : 0;
        __syncthreads();
        part[t] += u;
        __syncthreads();
    }
    if (i < N_NODES) excl[i] = part[t] - v;
    if (t == 255) bsum[blockIdx.x] = part[255];
}

__global__ __launch_bounds__(256) void scan_p2(int* __restrict__ bsum,
                                               int* __restrict__ rowptrN) {
    __shared__ int part[256];
    const int t = threadIdx.x;
    int v = (t < NBLK_SCAN) ? bsum[t] : 0;
    part[t] = v;
    __syncthreads();
#pragma unroll
    for (int off = 1; off < 256; off <<= 1) {
        int u = (t >= off) ? part[t - off] : 0;
        __syncthreads();
        part[t] += u;
        __syncthreads();
    }
    if (t < NBLK_SCAN) bsum[t] = part[t] - v;
    if (t == 255) *rowptrN = part[255];
}

__global__ __launch_bounds__(256) void scan_p3(const int* __restrict__ bsum,
                                               int* __restrict__ rowptr,
                                               int* __restrict__ cursor) {
    int i = blockIdx.x * 256 + threadIdx.x;
    if (i >= N_NODES) return;
    int r = rowptr[i] + bsum[blockIdx.x];
    rowptr[i] = r;
    cursor[i] = r;
}

__global__ __launch_bounds__(256) void fill_csr(const int* __restrict__ ei,
                                                const float* __restrict__ ew,
                                                int* __restrict__ cursor,
                                                int* __restrict__ sSrc,
                                                float* __restrict__ sW) {
    int e = blockIdx.x * 256 + threadIdx.x;
    if (e >= E_EDGES) return;
    int dst = ei[E_EDGES + e];
    int pos = atomicAdd(&cursor[dst], 1);
    sSrc[pos] = ei[e];
    sW[pos] = ew[e];
}

// ---------------------------------------------------------------------------
// agg[n,:] = sum_e w[e]*m[src[e],:]; one node/wave, index prefetch
// ---------------------------------------------------------------------------
__global__ __launch_bounds__(256) void gather_agg_bf16(const unsigned short* __restrict__ m,
                                                       const int* __restrict__ rowptr,
                                                       const int* __restrict__ sSrc,
                                                       const float* __restrict__ sW,
                                                       unsigned short* __restrict__ agg) {
    int wid = (blockIdx.x * 256 + threadIdx.x) >> 6;
    if (wid >= N_NODES) return;
    int lane = threadIdx.x & 63;
    int half = lane >> 5, li = lane & 31;
    int f0 = li << 2;
    int e0 = rowptr[wid], e1 = rowptr[wid + 1];
    float ax = 0.f, ay = 0.f, az = 0.f, aw = 0.f;
    int e = e0 + half;
    int s_nx = 0; float w_nx = 0.f;
    if (e < e1) { s_nx = sSrc[e]; w_nx = sW[e]; }
    for (; e < e1; e += 2) {
        int s = s_nx; float ww = w_nx;
        int en = e + 2;
        if (en < e1) { s_nx = sSrc[en]; w_nx = sW[en]; }
        ushort4 v = *(const ushort4*)(m + (size_t)s * KD + f0);
        ax += ww * bf2f(v.x); ay += ww * bf2f(v.y);
        az += ww * bf2f(v.z); aw += ww * bf2f(v.w);
    }
    ax += __shfl_xor(ax, 32, 64);
    ay += __shfl_xor(ay, 32, 64);
    az += __shfl_xor(az, 32, 64);
    aw += __shfl_xor(aw, 32, 64);
    if (half == 0) {
        ushort4 o;
        o.x = f2bf(ax); o.y = f2bf(ay); o.z = f2bf(az); o.w = f2bf(aw);
        *(ushort4*)(agg + (size_t)wid * KD + f0) = o;
    }
}

// ---------------------------------------------------------------------------
// m = h @ Wg. Weights staged once; pipelined grid-stride over row tiles.
// ---------------------------------------------------------------------------
__global__ __launch_bounds__(256) void mfma_gemm_m(const unsigned short* __restrict__ A,
                                                   const unsigned short* __restrict__ WT,
                                                   unsigned short* __restrict__ Mout) {
    __shared__ unsigned short wlds[32 * 512];
    const int lane = threadIdx.x & 63, wave = threadIdx.x >> 6;
    const int rl = lane & 15, kg = lane >> 4;
    for (int f = wave; f < 32; f += 4) {
        int jt = f >> 2, kk = f & 3;
        stage_frag(WT + (size_t)(jt * 16 + rl) * KD + kk * 32 + kg * 8, wlds + f * 512);
    }
    __syncthreads();
    const int stride = gridDim.x << 2;
    int rt = blockIdx.x * 4 + wave;
    if (rt >= RT_TILES) return;
    bf16x8 a[4];
#pragma unroll
    for (int kk = 0; kk < 4; ++kk)
        a[kk] = ldfrag(A + ((size_t)rt * 16 + rl) * KD + kk * 32 + kg * 8);
    while (rt < RT_TILES) {
        const int rtn = rt + stride;
        bf16x8 an[4];
        if (rtn < RT_TILES) {
#pragma unroll
            for (int kk = 0; kk < 4; ++kk)
                an[kk] = ldfrag(A + ((size_t)rtn * 16 + rl) * KD + kk * 32 + kg * 8);
        }
#pragma unroll
        for (int jt = 0; jt < 8; ++jt) {
            f32x4 acc = {0.f, 0.f, 0.f, 0.f};
#pragma unroll
            for (int kk = 0; kk < 4; ++kk)
                acc = __builtin_amdgcn_mfma_f32_16x16x32_bf16(
                    a[kk], ldfrag(wlds + (jt * 4 + kk) * 512 + lane * 8), acc, 0, 0, 0);
            int col = jt * 16 + rl;
#pragma unroll
            for (int p = 0; p < 4; ++p)
                Mout[(size_t)(rt * 16 + kg * 4 + p) * KD + col] = f2bf(acc[p]);
        }
        rt = rtn;
#pragma unroll
        for (int kk = 0; kk < 4; ++kk) a[kk] = an[kk];
    }
}

// ---------------------------------------------------------------------------
// Column-split fused GRU, pipelined A-loads, no inner barriers.
// ---------------------------------------------------------------------------
__global__ __launch_bounds__(256) void gru_fused(const unsigned short* __restrict__ Agg,
                                                 const unsigned short* __restrict__ Hin,
                                                 unsigned short* __restrict__ Hout,
                                                 const unsigned short* __restrict__ Wih,
                                                 const unsigned short* __restrict__ Whh,
                                                 const float* __restrict__ bih,
                                                 const float* __restrict__ bhh) {
    __shared__ unsigned short lds[24 * 512];
    const int lane = threadIdx.x & 63, wave = threadIdx.x >> 6;
    const int rl = lane & 15, kg = lane >> 4;
    const int col0 = blockIdx.y * 16;
    for (int q = wave; q < 24; q += 4) {
        int s = q >> 2, kk = q & 3;
        const unsigned short* src = (s < 3 ? Wih + (size_t)s * 128 * KD
                                           : Whh + (size_t)(s - 3) * 128 * KD)
                                    + (size_t)(col0 + rl) * KD + kk * 32 + kg * 8;
        stage_frag(src, lds + q * 512);
    }
    __syncthreads();
    const int col = col0 + rl;
    const float b_ir = bih[col], b_iz = bih[128 + col], b_in = bih[256 + col];
    const float b_hr = bhh[col], b_hz = bhh[128 + col], b_hn = bhh[256 + col];
    const int stride = gridDim.x << 2;
    int rt = blockIdx.x * 4 + wave;
    if (rt >= RT_TILES) return;
    bf16x8 a1[4], a2[4];
#pragma unroll
    for (int kk = 0; kk < 4; ++kk) {
        a1[kk] = ldfrag(Agg + ((size_t)rt * 16 + rl) * KD + kk * 32 + kg * 8);
        a2[kk] = ldfrag(Hin + ((size_t)rt * 16 + rl) * KD + kk * 32 + kg * 8);
    }
    while (rt < RT_TILES) {
        const int rtn = rt + stride;
        bf16x8 n1[4], n2[4];
        if (rtn < RT_TILES) {
#pragma unroll
            for (int kk = 0; kk < 4; ++kk) {
                n1[kk] = ldfrag(Agg + ((size_t)rtn * 16 + rl) * KD + kk * 32 + kg * 8);
                n2[kk] = ldfrag(Hin + ((size_t)rtn * 16 + rl) * KD + kk * 32 + kg * 8);
            }
        }
        f32x4 ir = {0.f,0.f,0.f,0.f}, iz = ir, in_ = ir, hr = ir, hz = ir, hn = ir;
#pragma unroll
        for (int kk = 0; kk < 4; ++kk) {
            ir  = __builtin_amdgcn_mfma_f32_16x16x32_bf16(a1[kk], ldfrag(lds + (0*4+kk)*512 + lane*8), ir,  0, 0, 0);
            iz  = __builtin_amdgcn_mfma_f32_16x16x32_bf16(a1[kk], ldfrag(lds + (1*4+kk)*512 + lane*8), iz,  0, 0, 0);
            in_ = __builtin_amdgcn_mfma_f32_16x16x32_bf16(a1[kk], ldfrag(lds + (2*4+kk)*512 + lane*8), in_, 0, 0, 0);
            hr  = __builtin_amdgcn_mfma_f32_16x16x32_bf16(a2[kk], ldfrag(lds + (3*4+kk)*512 + lane*8), hr,  0, 0, 0);
            hz  = __builtin_amdgcn_mfma_f32_16x16x32_bf16(a2[kk], ldfrag(lds + (4*4+kk)*512 + lane*8), hz,  0, 0, 0);
            hn  = __builtin_amdgcn_mfma_f32_16x16x32_bf16(a2[kk], ldfrag(lds + (5*4+kk)*512 + lane*8), hn,  0, 0, 0);
        }
#pragma unroll
        for (int p = 0; p < 4; ++p) {
            int row = rt * 16 + kg * 4 + p;
            float r = fsig(ir[p] + b_ir + hr[p] + b_hr);
            float z = fsig(iz[p] + b_iz + hz[p] + b_hz);
            float nc = ftanh(in_[p] + b_in + r * (hn[p] + b_hn));
            float hv = bf2f(Hin[(size_t)row * KD + col]);
            Hout[(size_t)row * KD + col] = f2bf((1.f - z) * nc + z * hv);
        }
        rt = rtn;
#pragma unroll
        for (int kk = 0; kk < 4; ++kk) { a1[kk] = n1[kk]; a2[kk] = n2[kk]; }
    }
}

// ---------------------------------------------------------------------------
// Column-split fused LSTM, pipelined A- and Cx-loads, no inner barriers.
// ---------------------------------------------------------------------------
__global__ __launch_bounds__(256) void lstm_fused(const unsigned short* __restrict__ Hh,
                                                  const unsigned short* __restrict__ Hx,
                                                  const float* __restrict__ Cx,
                                                  const unsigned short* __restrict__ Wih,
                                                  const unsigned short* __restrict__ Whh,
                                                  const float* __restrict__ bih,
                                                  const float* __restrict__ bhh,
                                                  float* __restrict__ h_out,
                                                  float* __restrict__ c_out,
                                                  unsigned short* __restrict__ Hrelu) {
    __shared__ unsigned short lds[32 * 512];
    const int lane = threadIdx.x & 63, wave = threadIdx.x >> 6;
    const int rl = lane & 15, kg = lane >> 4;
    const int col0 = blockIdx.y * 16;
    for (int q = wave; q < 32; q += 4) {
        int s = q >> 2, kk = q & 3;
        const unsigned short* src = (s < 4 ? Wih + (size_t)s * 128 * KD
                                           : Whh + (size_t)(s - 4) * 128 * KD)
                                    + (size_t)(col0 + rl) * KD + kk * 32 + kg * 8;
        stage_frag(src, lds + q * 512);
    }
    __syncthreads();
    const int col = col0 + rl;
    const float b_i = bih[col] + bhh[col];
    const float b_f = bih[128 + col] + bhh[128 + col];
    const float b_g = bih[256 + col] + bhh[256 + col];
    const float b_o = bih[384 + col] + bhh[384 + col];
    const int stride = gridDim.x << 2;
    int rt = blockIdx.x * 4 + wave;
    if (rt >= RT_TILES) return;
    bf16x8 a1[4], a2[4];
    float cpre[4];
#pragma unroll
    for (int kk = 0; kk < 4; ++kk) {
        a1[kk] = ldfrag(Hh + ((size_t)rt * 16 + rl) * KD + kk * 32 + kg * 8);
        a2[kk] = ldfrag(Hx + ((size_t)rt * 16 + rl) * KD + kk * 32 + kg * 8);
    }
#pragma unroll
    for (int p = 0; p < 4; ++p)
        cpre[p] = Cx[(size_t)(rt * 16 + kg * 4 + p) * KD + col];
    while (rt < RT_TILES) {
        const int rtn = rt + stride;
        bf16x8 n1[4], n2[4];
        float cnx[4];
        if (rtn < RT_TILES) {
#pragma unroll
            for (int kk = 0; kk < 4; ++kk) {
                n1[kk] = ldfrag(Hh + ((size_t)rtn * 16 + rl) * KD + kk * 32 + kg * 8);
                n2[kk] = ldfrag(Hx + ((size_t)rtn * 16 + rl) * KD + kk * 32 + kg * 8);
            }
#pragma unroll
            for (int p = 0; p < 4; ++p)
                cnx[p] = Cx[(size_t)(rtn * 16 + kg * 4 + p) * KD + col];
        }
        f32x4 gi = {0.f,0.f,0.f,0.f}, gf = gi, gg = gi, go = gi;
        f32x4 hi = gi, hf = gi, hg = gi, ho = gi;
#pragma unroll
        for (int kk = 0; kk < 4; ++kk) {
            gi = __builtin_amdgcn_mfma_f32_16x16x32_bf16(a1[kk], ldfrag(lds + (0*4+kk)*512 + lane*8), gi, 0, 0, 0);
            gf = __builtin_amdgcn_mfma_f32_16x16x32_bf16(a1[kk], ldfrag(lds + (1*4+kk)*512 + lane*8), gf, 0, 0, 0);
            gg = __builtin_amdgcn_mfma_f32_16x16x32_bf16(a1[kk], ldfrag(lds + (2*4+kk)*512 + lane*8), gg, 0, 0, 0);
            go = __builtin_amdgcn_mfma_f32_16x16x32_bf16(a1[kk], ldfrag(lds + (3*4+kk)*512 + lane*8), go, 0, 0, 0);
            hi = __builtin_amdgcn_mfma_f32_16x16x32_bf16(a2[kk], ldfrag(lds + (4*4+kk)*512 + lane*8), hi, 0, 0, 0);
            hf = __builtin_amdgcn_mfma_f32_16x16x32_bf16(a2[kk], ldfrag(lds + (5*4+kk)*512 + lane*8), hf, 0, 0, 0);
            hg = __builtin_amdgcn_mfma_f32_16x16x32_bf16(a2[kk], ldfrag(lds + (6*4+kk)*512 + lane*8), hg, 0, 0, 0);
            ho = __builtin_amdgcn_mfma_f32_16x16x32_bf16(a2[kk], ldfrag(lds + (7*4+kk)*512 + lane*8), ho, 0, 0, 0);
        }
#pragma unroll
        for (int p = 0; p < 4; ++p) {
            int row = rt * 16 + kg * 4 + p;
            size_t idx = (size_t)row * KD + col;
            float ig = fsig(gi[p] + hi[p] + b_i);
            float fg = fsig(gf[p] + hf[p] + b_f);
            float gv = ftanh(gg[p] + hg[p] + b_g);
            float og = fsig(go[p] + ho[p] + b_o);
            float c = fg * cpre[p] + ig * gv;
            float hn = og * ftanh(c);
            c_out[idx] = c;
            h_out[idx] = hn;
            Hrelu[idx] = f2bf(fmaxf(hn, 0.f));
        }
        rt = rtn;
#pragma unroll
        for (int kk = 0; kk < 4; ++kk) { a1[kk] = n1[kk]; a2[kk] = n2[kk]; }
#pragma unroll
        for (int p = 0; p < 4; ++p) cpre[p] = cnx[p];
    }
}

// ---------------------------------------------------------------------------
// head: out[N][64] = hrelu @ lin_wᵀ + lin_b; pipelined row-stride.
// ---------------------------------------------------------------------------
__global__ __launch_bounds__(256) void head_gemm(const unsigned short* __restrict__ Hr,
                                                 const unsigned short* __restrict__ LinW,
                                                 const float* __restrict__ lin_b,
                                                 float* __restrict__ Out) {
    __shared__ unsigned short wlds[16 * 512];
    const int lane = threadIdx.x & 63, wave = threadIdx.x >> 6;
    const int rl = lane & 15, kg = lane >> 4;
    for (int f = wave; f < 16; f += 4) {
        int jt = f >> 2, kk = f & 3;
        stage_frag(LinW + (size_t)(jt * 16 + rl) * KD + kk * 32 + kg * 8, wlds + f * 512);
    }
    __syncthreads();
    const int stride = gridDim.x << 2;
    int rt = blockIdx.x * 4 + wave;
    if (rt >= RT_TILES) return;
    bf16x8 a[4];
#pragma unroll
    for (int kk = 0; kk < 4; ++kk)
        a[kk] = ldfrag(Hr + ((size_t)rt * 16 + rl) * KD + kk * 32 + kg * 8);
    while (rt < RT_TILES) {
        const int rtn = rt + stride;
        bf16x8 an[4];
        if (rtn < RT_TILES) {
#pragma unroll
            for (int kk = 0; kk < 4; ++kk)
                an[kk] = ldfrag(Hr + ((size_t)rtn * 16 + rl) * KD + kk * 32 + kg * 8);
        }
#pragma unroll
        for (int jt = 0; jt < 4; ++jt) {
            f32x4 acc = {0.f, 0.f, 0.f, 0.f};
#pragma unroll
            for (int kk = 0; kk < 4; ++kk)
                acc = __builtin_amdgcn_mfma_f32_16x16x32_bf16(
                    a[kk], ldfrag(wlds + (jt * 4 + kk) * 512 + lane * 8), acc, 0, 0, 0);
            int col = jt * 16 + rl;
            float b = lin_b[col];
#pragma unroll
            for (int p = 0; p < 4; ++p)
                Out[(size_t)(rt * 16 + kg * 4 + p) * 64 + col] = acc[p] + b;
        }
        rt = rtn;
#pragma unroll
        for (int kk = 0; kk < 4; ++kk) a[kk] = an[kk];
    }
}

extern "C" void kernel_launch(void* const* d_in, const int* in_sizes, int n_in,
                              void* d_out, int out_size, void* d_ws, size_t ws_size,
                              hipStream_t stream) {
    const float* x        = (const float*)d_in[0];
    const int*   ei       = (const int*)d_in[1];
    const float* ew       = (const float*)d_in[2];
    const float* H        = (const float*)d_in[3];
    const float* C        = (const float*)d_in[4];
    const float* ggc_w    = (const float*)d_in[5];
    const float* gru_wih  = (const float*)d_in[6];
    const float* gru_whh  = (const float*)d_in[7];
    const float* gru_bih  = (const float*)d_in[8];
    const float* gru_bhh  = (const float*)d_in[9];
    const float* lstm_wih = (const float*)d_in[10];
    const float* lstm_whh = (const float*)d_in[11];
    const float* lstm_bih = (const float*)d_in[12];
    const float* lstm_bhh = (const float*)d_in[13];
    const float* lin_w    = (const float*)d_in[14];
    const float* lin_b    = (const float*)d_in[15];

    float* out_head = (float*)d_out;
    float* h_out = out_head + (size_t)N_NODES * 64;
    float* c_out = h_out + (size_t)N_NODES * KD;

    char* w = (char*)d_ws;
    unsigned short* hb    = (unsigned short*)w; w += (size_t)N_NODES * KD * 2;
    unsigned short* hb1   = (unsigned short*)w; w += (size_t)N_NODES * KD * 2;
    unsigned short* Hxb   = (unsigned short*)w; w += (size_t)N_NODES * KD * 2;
    unsigned short* mb    = (unsigned short*)w; w += (size_t)N_NODES * KD * 2;
    unsigned short* aggb  = (unsigned short*)w; w += (size_t)N_NODES * KD * 2;
    unsigned short* wgTb  = (unsigned short*)w; w += 2 * KD * KD * 2;
    unsigned short* wihb  = (unsigned short*)w; w += 384 * KD * 2;
    unsigned short* whhb  = (unsigned short*)w; w += 384 * KD * 2;
    unsigned short* lwihb = (unsigned short*)w; w += 512 * KD * 2;
    unsigned short* lwhhb = (unsigned short*)w; w += 512 * KD * 2;
    unsigned short* linwb = (unsigned short*)w; w += 64 * KD * 2;
    int*   rowptr = (int*)w; w += 50304 * 4;
    int*   cursor = (int*)w; w += 50304 * 4;
    int*   bsum   = (int*)w; w += 256 * 4;
    int*   sSrc   = (int*)w; w += (size_t)E_EDGES * 4;
    float* sW     = (float*)w; w += (size_t)E_EDGES * 4;

    dim3 blk(256);
    const int EB = (E_EDGES + 255) / 256;
    const int NF4 = N_NODES * KD / 4;
    const dim3 cellGrid(196, 8);

    cvt_xh<<<(2 * NF4 + 255) / 256, blk, 0, stream>>>(x, H, hb, Hxb, NF4);
    cvt_weights<<<(59392 + 255) / 256, blk, 0, stream>>>(
        gru_wih, gru_whh, lstm_wih, lstm_whh, lin_w,
        wihb, whhb, lwihb, lwhhb, linwb);
    transpose_wg_bf16<<<128, blk, 0, stream>>>(ggc_w, wgTb);

    hipMemsetAsync(cursor, 0, N_NODES * sizeof(int), stream);
    count_deg<<<EB, blk, 0, stream>>>(ei, cursor);
    scan_p1<<<NBLK_SCAN, blk, 0, stream>>>(cursor, rowptr, bsum);
    scan_p2<<<1, blk, 0, stream>>>(bsum, rowptr + N_NODES);
    scan_p3<<<NBLK_SCAN, blk, 0, stream>>>(bsum, rowptr, cursor);
    fill_csr<<<EB, blk, 0, stream>>>(ei, ew, cursor, sSrc, sW);

    mfma_gemm_m<<<391, blk, 0, stream>>>(hb, wgTb, mb);
    gather_agg_bf16<<<(N_NODES * 64 + 255) / 256, blk, 0, stream>>>(
        mb, rowptr, sSrc, sW, aggb);
    gru_fused<<<cellGrid, blk, 0, stream>>>(aggb, hb, hb1, wihb, whhb, gru_bih, gru_bhh);

    mfma_gemm_m<<<391, blk, 0, stream>>>(hb1, wgTb + (size_t)KD * KD, mb);
    gather_agg_bf16<<<(N_NODES * 64 + 255) / 256, blk, 0, stream>>>(
        mb, rowptr, sSrc, sW, aggb);
    gru_fused<<<cellGrid, blk, 0, stream>>>(aggb, hb1, hb, wihb, whhb, gru_bih, gru_bhh);

    lstm_fused<<<cellGrid, blk, 0, stream>>>(hb, Hxb, C, lwihb, lwhhb,
                                             lstm_bih, lstm_bhh, h_out, c_out, mb);
    head_gemm<<<391, blk, 0, stream>>>(mb, linwb, lin_b, out_head);
}